// Round 20
// baseline (213.584 us; speedup 1.0000x reference)
//
#include <hip/hip_runtime.h>
#include <hip/hip_bf16.h>

#define WCHUNK 16   // bitmap words per thread in scan kernels
#define EPB  4096   // edges per k_mebin block (grid 782 ~ 3/CU)
#define TPB_MB 512
#define BROWS 128   // rank-rows per bucket
#define BCAP 16384  // entry capacity per bucket (early buckets size-biased to ~8300
                    // mean; 8192 overflowed (r5/r6); 16384 ≈ 15σ)

typedef __attribute__((ext_vector_type(8))) short bhalf8;
typedef __attribute__((ext_vector_type(4))) float floatx4;

__device__ __forceinline__ unsigned short f2bf(float f) {
    __hip_bfloat16 h = __float2bfloat16(f);     // native RNE
    union { __hip_bfloat16 h; unsigned short u; } v;
    v.h = h;
    return v.u;
}

// ---------------- merged prep: xbf tiles | init pos/cursorb/bitmap | W1T/W2T (proven r17) ----------------
__global__ void k_preps(const float* __restrict__ x, unsigned short* __restrict__ xbf,
                        const float* __restrict__ W1, const float* __restrict__ W2,
                        unsigned short* __restrict__ W1T, unsigned short* __restrict__ W2T,
                        int* __restrict__ pos, int* __restrict__ cursorb,
                        unsigned long long* __restrict__ bitmap,
                        int N, int total4, int nbuck, int W, int E, int nb_x, int nb_i) {
    int bid = blockIdx.x;
    int tid = threadIdx.x;
    if (bid < nb_x) {
        // ---- prep_x: f32 -> bf16, tile-major, XOR-pre-swizzled, zero-padded ----
        int f = bid * 256 + tid;
        if (f >= total4) return;
        int tile = f >> 12;
        int row = (f >> 6) & 63;
        int c4 = (f & 63) * 4;
        int grow = tile * 64 + row;
        float4 v = (grow < N) ? *reinterpret_cast<const float4*>(x + (size_t)grow * 256 + c4)
                              : make_float4(0.f, 0.f, 0.f, 0.f);
        ushort4 bv;
        bv.x = f2bf(v.x); bv.y = f2bf(v.y); bv.z = f2bf(v.z); bv.w = f2bf(v.w);
        int uidx = (row * 256 + c4) ^ ((row & 7) << 3);
        *reinterpret_cast<ushort4*>(&xbf[(size_t)tile * 16384 + uidx]) = bv;
    } else if (bid < nb_x + nb_i) {
        // ---- init: pos = E; cursorb[b] = b*BCAP; bitmap = 0 ----
        int i = (bid - nb_x) * 256 + tid;
        if (i < N) pos[i] = E;
        if (i < nbuck) cursorb[i] = i * BCAP;
        if (i < W) bitmap[i] = 0ull;
    } else {
        // ---- prep: W1T/W2T bf16 transposed weights ----
        int i = (bid - nb_x - nb_i) * 256 + tid;
        if (i < 256 * 256) {
            int c = i >> 8, k = i & 255;
            W1T[i] = f2bf(W1[k * 256 + c]);     // W1T[c][k] = W1[k][c]
        }
        if (i < 48 * 320) {
            int c = i / 320, k = i % 320;
            W2T[i] = (c < 40) ? f2bf(W2[k * 40 + c]) : (unsigned short)0;
        }
    }
}

// ---------------- posmin over the FIRST Escan=min(N,E) edges only (proven r19) ----------------
// Proof: every consumed rank is for t = seg[seg[e]] with pos_full[t] <= seg[e] < N.
// If pos_full[n] < N it is attained within edges [0,N); else no bit below N set.
// Rank sets identical to the full-E scan.
__global__ void k_posmin(const int* __restrict__ ei, int* __restrict__ pos, int Escan) {
    int e = blockIdx.x * blockDim.x + threadIdx.x;
    if (e < Escan) {
        int s = ((const int2*)ei)[e].x;
        if (pos[s] > e) atomicMin(&pos[s], e);
    }
}

// ---------------- bitmap: set bit pos[n] for found nodes (proven) ----------------
__global__ void k_bitmap(const int* __restrict__ pos, unsigned long long* __restrict__ bitmap,
                         int N, int E) {
    int n = blockIdx.x * blockDim.x + threadIdx.x;
    if (n < N) {
        int p = pos[n];
        if (p < E) atomicOr(&bitmap[p >> 6], 1ull << (p & 63));
    }
}

// ---------------- per-block popcount sums over bitmap (proven r16) ----------------
__global__ void k_bitsum(const unsigned long long* __restrict__ bitmap,
                         int* __restrict__ bsum, int W) {
    __shared__ int sdata[256];
    int t = threadIdx.x;
    int base = (blockIdx.x * 256 + t) * WCHUNK;
    int cnt = 0;
    for (int l = 0; l < WCHUNK; l++) {
        int i = base + l;
        if (i < W) cnt += __popcll(bitmap[i]);
    }
    sdata[t] = cnt;
    __syncthreads();
    for (int s = 128; s > 0; s >>= 1) {
        if (t < s) sdata[t] += sdata[t + s];
        __syncthreads();
    }
    if (t == 0) bsum[blockIdx.x] = sdata[0];
}

// ---------------- exclusive scan of block sums (proven; nblk tiny) ----------------
__global__ void k_scanbsum(int* __restrict__ bsum, int nblk) {
    __shared__ int part[1024];
    const int T = 1024;
    int t = threadIdx.x;
    int per = (nblk + T - 1) / T;
    int s0 = t * per, s1 = min(s0 + per, nblk);
    int sum = 0;
    for (int i = s0; i < s1; i++) sum += bsum[i];
    part[t] = sum;
    __syncthreads();
    for (int off = 1; off < T; off <<= 1) {
        int v = 0;
        if (t >= off) v = part[t - off];
        __syncthreads();
        part[t] += v;
        __syncthreads();
    }
    int run = part[t] - sum;
    for (int i = s0; i < s1; i++) {
        int old = bsum[i];
        bsum[i] = run;
        run += old;
    }
    if (t == T - 1) bsum[nblk] = part[T - 1];
}

// ---------------- per-word exclusive popcount prefix (proven r16) ----------------
__global__ void k_wordpfx(const unsigned long long* __restrict__ bitmap,
                          const int* __restrict__ bsum, int* __restrict__ wordpfx, int W) {
    __shared__ int sdata[256];
    int t = threadIdx.x;
    int base = (blockIdx.x * 256 + t) * WCHUNK;
    int cnt = 0;
    for (int l = 0; l < WCHUNK; l++) {
        int i = base + l;
        if (i < W) cnt += __popcll(bitmap[i]);
    }
    sdata[t] = cnt;
    __syncthreads();
    for (int off = 1; off < 256; off <<= 1) {
        int v = 0;
        if (t >= off) v = sdata[t - off];
        __syncthreads();
        sdata[t] += v;
        __syncthreads();
    }
    int run = bsum[blockIdx.x] + sdata[t] - cnt;   // exclusive start for this thread
    for (int l = 0; l < WCHUNK; l++) {
        int i = base + l;
        if (i >= W) break;
        wordpfx[i] = run;
        run += __popcll(bitmap[i]);
    }
}

// ---------------- rank[n] = # set bits strictly below bit pos[n] (proven r15/16) ----------------
__global__ void k_rank_bm(const int* __restrict__ pos, const unsigned long long* __restrict__ bitmap,
                          const int* __restrict__ wordpfx, int* __restrict__ rank, int N, int E) {
    int n = blockIdx.x * blockDim.x + threadIdx.x;
    if (n >= N) return;
    int p = pos[n];
    if (p < E) {
        int w = p >> 6, off = p & 63;
        unsigned long long mask = (1ull << off) - 1ull;   // off in [0,63]
        rank[n] = wordpfx[w] + __popcll(bitmap[w] & mask);
    }
}

// ---------------- mebin: fused gather + bucket binning, LDS-staged ----------------
// r20: EPB 4096 (grid 782 ~ 3/CU, fixes r18's grid-limited 1.5/CU) + bounds (512,4)
// (fixes r19's VGPR=24 starvation: budget 128 -> ~40 regs, full 4-wide ILP).
__global__ __launch_bounds__(TPB_MB, 4) void k_mebin(const int* __restrict__ ei,
                                                     const int* __restrict__ rank,
                                                     const int* __restrict__ ef,
                                                     int* __restrict__ cursorb,
                                                     unsigned* __restrict__ binned,
                                                     int E, int nbuck) {
    __shared__ unsigned lmp[EPB];          // 16KB: (m<<16)|pv per staged edge
    __shared__ int lcnt[800];
    __shared__ int lbase[800];
    __shared__ int lfill[800];
    int tid = threadIdx.x;
    int base = blockIdx.x * EPB;
    for (int b = tid; b < nbuck; b += TPB_MB) { lcnt[b] = 0; lfill[b] = 0; }
    __syncthreads();
    // gather + stage + count: 8 edges/thread in 2 batches of 4 independent chains
#pragma unroll
    for (int jj = 0; jj < 2; jj++) {
        int l0 = (jj * 4 + 0) * TPB_MB + tid;
        int l1 = (jj * 4 + 1) * TPB_MB + tid;
        int l2 = (jj * 4 + 2) * TPB_MB + tid;
        int l3 = (jj * 4 + 3) * TPB_MB + tid;
        int e0 = base + l0, e1 = base + l1, e2 = base + l2, e3 = base + l3;
        int s0 = 0, s1 = 0, s2 = 0, s3 = 0;
        if (e0 < E) s0 = ((const int2*)ei)[e0].x;
        if (e1 < E) s1 = ((const int2*)ei)[e1].x;
        if (e2 < E) s2 = ((const int2*)ei)[e2].x;
        if (e3 < E) s3 = ((const int2*)ei)[e3].x;
        int t0 = 0, t1 = 0, t2 = 0, t3 = 0;
        if (e0 < E) t0 = ((const int2*)ei)[s0].x;
        if (e1 < E) t1 = ((const int2*)ei)[s1].x;
        if (e2 < E) t2 = ((const int2*)ei)[s2].x;
        if (e3 < E) t3 = ((const int2*)ei)[s3].x;
        int m0 = 0, m1 = 0, m2 = 0, m3 = 0;
        if (e0 < E) m0 = rank[t0];
        if (e1 < E) m1 = rank[t1];
        if (e2 < E) m2 = rank[t2];
        if (e3 < E) m3 = rank[t3];
        int4 f0, f1, f2, f3;
        if (e0 < E) f0 = *reinterpret_cast<const int4*>(ef + 4 * (size_t)e0);
        if (e1 < E) f1 = *reinterpret_cast<const int4*>(ef + 4 * (size_t)e1);
        if (e2 < E) f2 = *reinterpret_cast<const int4*>(ef + 4 * (size_t)e2);
        if (e3 < E) f3 = *reinterpret_cast<const int4*>(ef + 4 * (size_t)e3);
        if (e0 < E) { lmp[l0] = ((unsigned)m0 << 16) | (unsigned)(f0.x | (f0.y << 4) | (f0.z << 8) | (f0.w << 12)); atomicAdd(&lcnt[m0 >> 7], 1); }
        if (e1 < E) { lmp[l1] = ((unsigned)m1 << 16) | (unsigned)(f1.x | (f1.y << 4) | (f1.z << 8) | (f1.w << 12)); atomicAdd(&lcnt[m1 >> 7], 1); }
        if (e2 < E) { lmp[l2] = ((unsigned)m2 << 16) | (unsigned)(f2.x | (f2.y << 4) | (f2.z << 8) | (f2.w << 12)); atomicAdd(&lcnt[m2 >> 7], 1); }
        if (e3 < E) { lmp[l3] = ((unsigned)m3 << 16) | (unsigned)(f3.x | (f3.y << 4) | (f3.z << 8) | (f3.w << 12)); atomicAdd(&lcnt[m3 >> 7], 1); }
    }
    __syncthreads();
    // claim contiguous global runs per bucket
    for (int b = tid; b < nbuck; b += TPB_MB) {
        int c = lcnt[b];
        lbase[b] = (c > 0) ? atomicAdd(&cursorb[b], c) : 0;
    }
    __syncthreads();
    // write from LDS only
#pragma unroll
    for (int j = 0; j < EPB / TPB_MB; j++) {
        int li = j * TPB_MB + tid;
        if (base + li < E) {
            unsigned v = lmp[li];
            int b = v >> 23;
            int off = atomicAdd(&lfill[b], 1);
            long long slot = (long long)lbase[b] + off;
            if (slot < (long long)(b + 1) * BCAP)   // overflow guard
                binned[slot] = v & 0x7FFFFFu;       // (m&127)<<16 | pv
        }
    }
}

// ---------------- bucket gather: LDS histogram -> bf16 pre-swizzled agg tiles (proven) ----------------
__global__ __launch_bounds__(256) void k_bgather(const int* __restrict__ cursorb,
                                                 const unsigned* __restrict__ binned,
                                                 unsigned short* __restrict__ aggbf, int N) {
    __shared__ int hist[BROWS * 64];   // 32KB
    int tid = threadIdx.x;
    int b = blockIdx.x;
    int m0 = b * BROWS;
    for (int i = tid; i < BROWS * 64; i += 256) hist[i] = 0;
    __syncthreads();
    int r0 = b * BCAP;
    int r1 = min(cursorb[b], (b + 1) * BCAP);
    for (int i = r0 + tid; i < r1; i += 256) {
        unsigned v = binned[i];
        int lr = (int)(v >> 16) << 6;           // local row (m&127) * 64
        atomicAdd(&hist[lr + (v & 15u)], 1);
        atomicAdd(&hist[lr + 16 + ((v >> 4) & 15u)], 1);
        atomicAdd(&hist[lr + 32 + ((v >> 8) & 15u)], 1);
        atomicAdd(&hist[lr + 48 + ((v >> 12) & 15u)], 1);
    }
    __syncthreads();
    int rows = min(BROWS, N - m0);
    for (int i = tid; i < rows * 64; i += 256) {
        int lr = i >> 6, col = i & 63;
        int tile = (m0 + lr) >> 6;
        int row = (m0 + lr) & 63;
        int uidx = (row * 64 + col) ^ ((row & 7) << 3);
        aggbf[(size_t)tile * 4096 + uidx] = f2bf((float)hist[i]);
    }
}

// ---------------- fused MFMA (r13/r14/r16 proven: async global_load_lds staging) ----------------
__global__ __launch_bounds__(512) void k_fused(const unsigned short* __restrict__ xbf,
                                               const unsigned short* __restrict__ W1T,
                                               const float* __restrict__ b1,
                                               const unsigned short* __restrict__ W2T,
                                               const float* __restrict__ b2,
                                               const unsigned short* __restrict__ aggbf,
                                               float* __restrict__ out, int N) {
    __shared__ __align__(16) unsigned short xs[64 * 256];
    __shared__ __align__(16) unsigned short as[64 * 64];
    int tid = threadIdx.x;
    int lane = tid & 63;
    int w = tid >> 6;
    int lrow = lane & 15, lkb = lane >> 4;
    int n0 = blockIdx.x * 64;

    {
        const char* xg = (const char*)(xbf + (size_t)blockIdx.x * 16384);
#pragma unroll
        for (int j = 0; j < 4; j++) {
            int ch = w * 4 + j;
            __builtin_amdgcn_global_load_lds(
                (const __attribute__((address_space(1))) unsigned*)(xg + ch * 1024 + lane * 16),
                (__attribute__((address_space(3))) unsigned*)((char*)xs + ch * 1024),
                16, 0, 0);
        }
        const char* ag = (const char*)(aggbf + (size_t)blockIdx.x * 4096);
        __builtin_amdgcn_global_load_lds(
            (const __attribute__((address_space(1))) unsigned*)(ag + w * 1024 + lane * 16),
            (__attribute__((address_space(3))) unsigned*)((char*)as + w * 1024),
            16, 0, 0);
    }
    __syncthreads();

    int wc0 = w * 32;
    floatx4 acc1[4][2];
#pragma unroll
    for (int mt = 0; mt < 4; mt++)
#pragma unroll
        for (int nt = 0; nt < 2; nt++) acc1[mt][nt] = (floatx4){0.f, 0.f, 0.f, 0.f};
    float b1v[2];
#pragma unroll
    for (int nt = 0; nt < 2; nt++) b1v[nt] = b1[wc0 + nt * 16 + lrow];

#pragma unroll
    for (int ks = 0; ks < 8; ks++) {
        int koff = ks * 32 + lkb * 8;
        bhalf8 af[4], bf[2];
#pragma unroll
        for (int mt = 0; mt < 4; mt++) {
            int row = mt * 16 + lrow;
            int uidx = (row * 256 + koff) ^ ((row & 7) << 3);
            af[mt] = *reinterpret_cast<const bhalf8*>(&xs[uidx]);
        }
#pragma unroll
        for (int nt = 0; nt < 2; nt++) {
            int col = wc0 + nt * 16 + lrow;
            bf[nt] = *reinterpret_cast<const bhalf8*>(&W1T[(size_t)col * 256 + koff]);
        }
#pragma unroll
        for (int mt = 0; mt < 4; mt++)
#pragma unroll
            for (int nt = 0; nt < 2; nt++)
                acc1[mt][nt] = __builtin_amdgcn_mfma_f32_16x16x32_bf16(af[mt], bf[nt], acc1[mt][nt], 0, 0, 0);
    }
    __syncthreads();

#pragma unroll
    for (int mt = 0; mt < 4; mt++)
#pragma unroll
        for (int nt = 0; nt < 2; nt++) {
            int col = wc0 + nt * 16 + lrow;
#pragma unroll
            for (int r = 0; r < 4; r++) {
                int row = mt * 16 + lkb * 4 + r;
                float v = fmaxf(acc1[mt][nt][r] + b1v[nt], 0.f);
                int uidx = (row * 256 + col) ^ ((row & 7) << 3);
                xs[uidx] = f2bf(v);
            }
        }
    __syncthreads();

    int r0 = (w >> 1) * 16;
    int odd = w & 1;
    floatx4 acc2[2];
    acc2[0] = (floatx4){0.f, 0.f, 0.f, 0.f};
    acc2[1] = (floatx4){0.f, 0.f, 0.f, 0.f};
    int c0 = odd ? 32 : 0;
#pragma unroll
    for (int ks = 0; ks < 8; ks++) {
        int koff = ks * 32 + lkb * 8;
        int row = r0 + lrow;
        int uidx = (row * 256 + koff) ^ ((row & 7) << 3);
        bhalf8 a = *reinterpret_cast<const bhalf8*>(&xs[uidx]);
        bhalf8 b0 = *reinterpret_cast<const bhalf8*>(&W2T[(size_t)(c0 + lrow) * 320 + koff]);
        acc2[0] = __builtin_amdgcn_mfma_f32_16x16x32_bf16(a, b0, acc2[0], 0, 0, 0);
        if (!odd) {
            bhalf8 b1f = *reinterpret_cast<const bhalf8*>(&W2T[(size_t)(16 + lrow) * 320 + koff]);
            acc2[1] = __builtin_amdgcn_mfma_f32_16x16x32_bf16(a, b1f, acc2[1], 0, 0, 0);
        }
    }
#pragma unroll
    for (int ks = 0; ks < 2; ks++) {
        int koff = ks * 32 + lkb * 8;
        int row = r0 + lrow;
        int uidx = (row * 64 + koff) ^ ((row & 7) << 3);
        bhalf8 a = *reinterpret_cast<const bhalf8*>(&as[uidx]);
        bhalf8 b0 = *reinterpret_cast<const bhalf8*>(&W2T[(size_t)(c0 + lrow) * 320 + 256 + koff]);
        acc2[0] = __builtin_amdgcn_mfma_f32_16x16x32_bf16(a, b0, acc2[0], 0, 0, 0);
        if (!odd) {
            bhalf8 b1f = *reinterpret_cast<const bhalf8*>(&W2T[(size_t)(16 + lrow) * 320 + 256 + koff]);
            acc2[1] = __builtin_amdgcn_mfma_f32_16x16x32_bf16(a, b1f, acc2[1], 0, 0, 0);
        }
    }
    int ntend = odd ? 1 : 2;
#pragma unroll
    for (int nt = 0; nt < 2; nt++) {
        if (nt >= ntend) continue;
        int col = c0 + nt * 16 + lrow;
        if (col >= 40) continue;
        float bb = b2[col];
#pragma unroll
        for (int r = 0; r < 4; r++) {
            int row = n0 + r0 + lkb * 4 + r;
            if (row < N) out[(size_t)row * 40 + col] = acc2[nt][r] + bb;
        }
    }
}

extern "C" void kernel_launch(void* const* d_in, const int* in_sizes, int n_in,
                              void* d_out, int out_size, void* d_ws, size_t ws_size,
                              hipStream_t stream) {
    const float* x  = (const float*)d_in[0];
    const int*   ei = (const int*)d_in[1];
    const int*   ef = (const int*)d_in[2];
    const float* W1 = (const float*)d_in[3];
    const float* b1 = (const float*)d_in[4];
    const float* W2 = (const float*)d_in[5];
    const float* b2 = (const float*)d_in[6];
    float* out = (float*)d_out;

    const int HID = in_sizes[4];            // 256
    const int D   = in_sizes[3] / HID;      // 256
    const int N   = in_sizes[0] / D;        // 100000
    const int E   = in_sizes[1] / 2;        // 3200000
    (void)HID; (void)D;

    const int Escan  = min(N, E);                   // posmin truncation (r19 proof)
    const int nbuck  = (N + BROWS - 1) / BROWS;     // 782
    const int ntiles = (N + 63) / 64;               // 1563
    const int W      = (Escan + 63) / 64;           // 1563 bitmap words
    const int nblk_w = (W + 4096 - 1) / 4096;       // 1

    // workspace layout, 4-byte units (d_ws 16B-aligned); total ~117MB
    int* ws = (int*)d_ws;
    size_t o = 0;
    unsigned short* aggbf = (unsigned short*)(ws + o); o += (size_t)ntiles * 2048;
    int* pos = ws + o;                               o += N;
    int* rank = ws + o;                              o += N;
    int* cursorb = ws + o;                           o += nbuck;
    int* bsum_w = ws + o;                            o += nblk_w + 1;
    o = (o + 1) & ~(size_t)1;                        // 8B align for bitmap
    unsigned long long* bitmap = (unsigned long long*)(ws + o); o += 2 * (size_t)W;
    int* wordpfx = ws + o;                           o += W + 1;
    o = (o + 3) & ~(size_t)3;                        // 16B align
    unsigned* binned = (unsigned*)(ws + o);          o += (size_t)nbuck * BCAP;
    unsigned short* W1T = (unsigned short*)(ws + o); o += 32768;
    unsigned short* W2T = (unsigned short*)(ws + o); o += 7680;
    unsigned short* xbf = (unsigned short*)(ws + o); o += (size_t)ntiles * 8192;

    const int total4 = ntiles * 4096;
    const int nb_x = (total4 + 255) / 256;          // 25008 prep_x blocks
    const int nb_i = (max(max(N, W), nbuck) + 255) / 256;  // 391 init blocks
    const int nb_w = 256;                           // weight-prep blocks (covers 65536 idx)

    hipLaunchKernelGGL(k_preps, dim3(nb_x + nb_i + nb_w), dim3(256), 0, stream,
                       x, xbf, W1, W2, W1T, W2T, pos, cursorb, bitmap,
                       N, total4, nbuck, W, E, nb_x, nb_i);
    hipLaunchKernelGGL(k_posmin, dim3((Escan + 255) / 256), dim3(256), 0, stream, ei, pos, Escan);
    hipLaunchKernelGGL(k_bitmap, dim3((N + 255) / 256), dim3(256), 0, stream, pos, bitmap, N, E);
    hipLaunchKernelGGL(k_bitsum, dim3(nblk_w), dim3(256), 0, stream, bitmap, bsum_w, W);
    hipLaunchKernelGGL(k_scanbsum, dim3(1), dim3(1024), 0, stream, bsum_w, nblk_w);
    hipLaunchKernelGGL(k_wordpfx, dim3(nblk_w), dim3(256), 0, stream, bitmap, bsum_w, wordpfx, W);
    hipLaunchKernelGGL(k_rank_bm, dim3((N + 255) / 256), dim3(256), 0, stream, pos, bitmap, wordpfx, rank, N, E);
    hipLaunchKernelGGL(k_mebin, dim3((E + EPB - 1) / EPB), dim3(TPB_MB), 0, stream,
                       ei, rank, ef, cursorb, binned, E, nbuck);
    hipLaunchKernelGGL(k_bgather, dim3(nbuck), dim3(256), 0, stream, cursorb, binned, aggbf, N);
    hipLaunchKernelGGL(k_fused, dim3(ntiles), dim3(512), 0, stream,
                       xbf, W1T, b1, W2T, b2, aggbf, out, N);
}

// Round 21
// 189.257 us; speedup vs baseline: 1.1285x; 1.1285x over previous
//
#include <hip/hip_runtime.h>
#include <hip/hip_bf16.h>

#define WCHUNK 16   // bitmap words per thread in scan kernels
#define EPB  8192   // edges per k_mebin block (r18-proven: VGPR=40, long runs)
#define TPB_MB 512
#define BROWS 128   // rank-rows per bucket
#define BCAP 16384  // entry capacity per bucket (early buckets size-biased to ~8300
                    // mean; 8192 overflowed (r5/r6); 16384 ≈ 15σ)

typedef __attribute__((ext_vector_type(8))) short bhalf8;
typedef __attribute__((ext_vector_type(4))) float floatx4;

__device__ __forceinline__ unsigned short f2bf(float f) {
    __hip_bfloat16 h = __float2bfloat16(f);     // native RNE
    union { __hip_bfloat16 h; unsigned short u; } v;
    v.h = h;
    return v.u;
}

// ---------------- merged prep: xbf tiles | init pos/cursorb/bitmap | W1T/W2T (proven r17) ----------------
__global__ void k_preps(const float* __restrict__ x, unsigned short* __restrict__ xbf,
                        const float* __restrict__ W1, const float* __restrict__ W2,
                        unsigned short* __restrict__ W1T, unsigned short* __restrict__ W2T,
                        int* __restrict__ pos, int* __restrict__ cursorb,
                        unsigned long long* __restrict__ bitmap,
                        int N, int total4, int nbuck, int W, int E, int nb_x, int nb_i) {
    int bid = blockIdx.x;
    int tid = threadIdx.x;
    if (bid < nb_x) {
        // ---- prep_x: f32 -> bf16, tile-major, XOR-pre-swizzled, zero-padded ----
        int f = bid * 256 + tid;
        if (f >= total4) return;
        int tile = f >> 12;
        int row = (f >> 6) & 63;
        int c4 = (f & 63) * 4;
        int grow = tile * 64 + row;
        float4 v = (grow < N) ? *reinterpret_cast<const float4*>(x + (size_t)grow * 256 + c4)
                              : make_float4(0.f, 0.f, 0.f, 0.f);
        ushort4 bv;
        bv.x = f2bf(v.x); bv.y = f2bf(v.y); bv.z = f2bf(v.z); bv.w = f2bf(v.w);
        int uidx = (row * 256 + c4) ^ ((row & 7) << 3);
        *reinterpret_cast<ushort4*>(&xbf[(size_t)tile * 16384 + uidx]) = bv;
    } else if (bid < nb_x + nb_i) {
        // ---- init: pos = E; cursorb[b] = b*BCAP; bitmap = 0 ----
        int i = (bid - nb_x) * 256 + tid;
        if (i < N) pos[i] = E;
        if (i < nbuck) cursorb[i] = i * BCAP;
        if (i < W) bitmap[i] = 0ull;
    } else {
        // ---- prep: W1T/W2T bf16 transposed weights ----
        int i = (bid - nb_x - nb_i) * 256 + tid;
        if (i < 256 * 256) {
            int c = i >> 8, k = i & 255;
            W1T[i] = f2bf(W1[k * 256 + c]);     // W1T[c][k] = W1[k][c]
        }
        if (i < 48 * 320) {
            int c = i / 320, k = i % 320;
            W2T[i] = (c < 40) ? f2bf(W2[k * 40 + c]) : (unsigned short)0;
        }
    }
}

// ---------------- posmin over the FIRST Escan=min(N,E) edges only (proven r19) ----------------
__global__ void k_posmin(const int* __restrict__ ei, int* __restrict__ pos, int Escan) {
    int e = blockIdx.x * blockDim.x + threadIdx.x;
    if (e < Escan) {
        int s = ((const int2*)ei)[e].x;
        if (pos[s] > e) atomicMin(&pos[s], e);
    }
}

// ---------------- bitmap: set bit pos[n] for found nodes (proven) ----------------
__global__ void k_bitmap(const int* __restrict__ pos, unsigned long long* __restrict__ bitmap,
                         int N, int E) {
    int n = blockIdx.x * blockDim.x + threadIdx.x;
    if (n < N) {
        int p = pos[n];
        if (p < E) atomicOr(&bitmap[p >> 6], 1ull << (p & 63));
    }
}

// ---------------- per-block popcount sums over bitmap (proven r16) ----------------
__global__ void k_bitsum(const unsigned long long* __restrict__ bitmap,
                         int* __restrict__ bsum, int W) {
    __shared__ int sdata[256];
    int t = threadIdx.x;
    int base = (blockIdx.x * 256 + t) * WCHUNK;
    int cnt = 0;
    for (int l = 0; l < WCHUNK; l++) {
        int i = base + l;
        if (i < W) cnt += __popcll(bitmap[i]);
    }
    sdata[t] = cnt;
    __syncthreads();
    for (int s = 128; s > 0; s >>= 1) {
        if (t < s) sdata[t] += sdata[t + s];
        __syncthreads();
    }
    if (t == 0) bsum[blockIdx.x] = sdata[0];
}

// ---------------- exclusive scan of block sums (proven; nblk tiny) ----------------
__global__ void k_scanbsum(int* __restrict__ bsum, int nblk) {
    __shared__ int part[1024];
    const int T = 1024;
    int t = threadIdx.x;
    int per = (nblk + T - 1) / T;
    int s0 = t * per, s1 = min(s0 + per, nblk);
    int sum = 0;
    for (int i = s0; i < s1; i++) sum += bsum[i];
    part[t] = sum;
    __syncthreads();
    for (int off = 1; off < T; off <<= 1) {
        int v = 0;
        if (t >= off) v = part[t - off];
        __syncthreads();
        part[t] += v;
        __syncthreads();
    }
    int run = part[t] - sum;
    for (int i = s0; i < s1; i++) {
        int old = bsum[i];
        bsum[i] = run;
        run += old;
    }
    if (t == T - 1) bsum[nblk] = part[T - 1];
}

// ---------------- per-word exclusive popcount prefix (proven r16) ----------------
__global__ void k_wordpfx(const unsigned long long* __restrict__ bitmap,
                          const int* __restrict__ bsum, int* __restrict__ wordpfx, int W) {
    __shared__ int sdata[256];
    int t = threadIdx.x;
    int base = (blockIdx.x * 256 + t) * WCHUNK;
    int cnt = 0;
    for (int l = 0; l < WCHUNK; l++) {
        int i = base + l;
        if (i < W) cnt += __popcll(bitmap[i]);
    }
    sdata[t] = cnt;
    __syncthreads();
    for (int off = 1; off < 256; off <<= 1) {
        int v = 0;
        if (t >= off) v = sdata[t - off];
        __syncthreads();
        sdata[t] += v;
        __syncthreads();
    }
    int run = bsum[blockIdx.x] + sdata[t] - cnt;   // exclusive start for this thread
    for (int l = 0; l < WCHUNK; l++) {
        int i = base + l;
        if (i >= W) break;
        wordpfx[i] = run;
        run += __popcll(bitmap[i]);
    }
}

// ---------------- rank[n] = # set bits strictly below bit pos[n] (proven r15/16) ----------------
__global__ void k_rank_bm(const int* __restrict__ pos, const unsigned long long* __restrict__ bitmap,
                          const int* __restrict__ wordpfx, int* __restrict__ rank, int N, int E) {
    int n = blockIdx.x * blockDim.x + threadIdx.x;
    if (n >= N) return;
    int p = pos[n];
    if (p < E) {
        int w = p >> 6, off = p & 63;
        unsigned long long mask = (1ull << off) - 1ull;   // off in [0,63]
        rank[n] = wordpfx[w] + __popcll(bitmap[w] & mask);
    }
}

// ---------------- rt[n] = rank[seg[n]]: collapses mebin's chain from 3 loads to 2 ----------------
// Valid: for n < N, seg[n] is present (pos[seg[n]] <= n < N), so rank[seg[n]] is defined.
__global__ void k_rt(const int* __restrict__ ei, const int* __restrict__ rank,
                     int* __restrict__ rt, int N) {
    int n = blockIdx.x * blockDim.x + threadIdx.x;
    if (n < N) rt[n] = rank[((const int2*)ei)[n].x];
}

// ---------------- mebin: gather + bucket binning, LDS-staged (r18 geometry + rt chain) ----------------
// Per edge: s = ei[e].x (coalesced) -> m = rt[s] (ONE random L2 gather; r20 had two).
__global__ __launch_bounds__(TPB_MB, 4) void k_mebin(const int* __restrict__ ei,
                                                     const int* __restrict__ rt,
                                                     const int* __restrict__ ef,
                                                     int* __restrict__ cursorb,
                                                     unsigned* __restrict__ binned,
                                                     int E, int nbuck) {
    __shared__ unsigned lmp[EPB];          // 32KB: (m<<16)|pv per staged edge
    __shared__ int lcnt[800];
    __shared__ int lbase[800];
    __shared__ int lfill[800];
    int tid = threadIdx.x;
    int base = blockIdx.x * EPB;
    for (int b = tid; b < nbuck; b += TPB_MB) { lcnt[b] = 0; lfill[b] = 0; }
    __syncthreads();
    // gather + stage + count: 16 edges/thread in 4 batches of 4 independent chains
#pragma unroll
    for (int jj = 0; jj < 4; jj++) {
        int l0 = (jj * 4 + 0) * TPB_MB + tid;
        int l1 = (jj * 4 + 1) * TPB_MB + tid;
        int l2 = (jj * 4 + 2) * TPB_MB + tid;
        int l3 = (jj * 4 + 3) * TPB_MB + tid;
        int e0 = base + l0, e1 = base + l1, e2 = base + l2, e3 = base + l3;
        int s0 = 0, s1 = 0, s2 = 0, s3 = 0;
        if (e0 < E) s0 = ((const int2*)ei)[e0].x;
        if (e1 < E) s1 = ((const int2*)ei)[e1].x;
        if (e2 < E) s2 = ((const int2*)ei)[e2].x;
        if (e3 < E) s3 = ((const int2*)ei)[e3].x;
        int m0 = 0, m1 = 0, m2 = 0, m3 = 0;
        if (e0 < E) m0 = rt[s0];
        if (e1 < E) m1 = rt[s1];
        if (e2 < E) m2 = rt[s2];
        if (e3 < E) m3 = rt[s3];
        int4 f0, f1, f2, f3;
        if (e0 < E) f0 = *reinterpret_cast<const int4*>(ef + 4 * (size_t)e0);
        if (e1 < E) f1 = *reinterpret_cast<const int4*>(ef + 4 * (size_t)e1);
        if (e2 < E) f2 = *reinterpret_cast<const int4*>(ef + 4 * (size_t)e2);
        if (e3 < E) f3 = *reinterpret_cast<const int4*>(ef + 4 * (size_t)e3);
        if (e0 < E) { lmp[l0] = ((unsigned)m0 << 16) | (unsigned)(f0.x | (f0.y << 4) | (f0.z << 8) | (f0.w << 12)); atomicAdd(&lcnt[m0 >> 7], 1); }
        if (e1 < E) { lmp[l1] = ((unsigned)m1 << 16) | (unsigned)(f1.x | (f1.y << 4) | (f1.z << 8) | (f1.w << 12)); atomicAdd(&lcnt[m1 >> 7], 1); }
        if (e2 < E) { lmp[l2] = ((unsigned)m2 << 16) | (unsigned)(f2.x | (f2.y << 4) | (f2.z << 8) | (f2.w << 12)); atomicAdd(&lcnt[m2 >> 7], 1); }
        if (e3 < E) { lmp[l3] = ((unsigned)m3 << 16) | (unsigned)(f3.x | (f3.y << 4) | (f3.z << 8) | (f3.w << 12)); atomicAdd(&lcnt[m3 >> 7], 1); }
    }
    __syncthreads();
    // claim contiguous global runs per bucket
    for (int b = tid; b < nbuck; b += TPB_MB) {
        int c = lcnt[b];
        lbase[b] = (c > 0) ? atomicAdd(&cursorb[b], c) : 0;
    }
    __syncthreads();
    // write from LDS only
#pragma unroll
    for (int j = 0; j < EPB / TPB_MB; j++) {
        int li = j * TPB_MB + tid;
        if (base + li < E) {
            unsigned v = lmp[li];
            int b = v >> 23;
            int off = atomicAdd(&lfill[b], 1);
            long long slot = (long long)lbase[b] + off;
            if (slot < (long long)(b + 1) * BCAP)   // overflow guard
                binned[slot] = v & 0x7FFFFFu;       // (m&127)<<16 | pv
        }
    }
}

// ---------------- bucket gather: LDS histogram -> bf16 pre-swizzled agg tiles (proven) ----------------
__global__ __launch_bounds__(256) void k_bgather(const int* __restrict__ cursorb,
                                                 const unsigned* __restrict__ binned,
                                                 unsigned short* __restrict__ aggbf, int N) {
    __shared__ int hist[BROWS * 64];   // 32KB
    int tid = threadIdx.x;
    int b = blockIdx.x;
    int m0 = b * BROWS;
    for (int i = tid; i < BROWS * 64; i += 256) hist[i] = 0;
    __syncthreads();
    int r0 = b * BCAP;
    int r1 = min(cursorb[b], (b + 1) * BCAP);
    for (int i = r0 + tid; i < r1; i += 256) {
        unsigned v = binned[i];
        int lr = (int)(v >> 16) << 6;           // local row (m&127) * 64
        atomicAdd(&hist[lr + (v & 15u)], 1);
        atomicAdd(&hist[lr + 16 + ((v >> 4) & 15u)], 1);
        atomicAdd(&hist[lr + 32 + ((v >> 8) & 15u)], 1);
        atomicAdd(&hist[lr + 48 + ((v >> 12) & 15u)], 1);
    }
    __syncthreads();
    int rows = min(BROWS, N - m0);
    for (int i = tid; i < rows * 64; i += 256) {
        int lr = i >> 6, col = i & 63;
        int tile = (m0 + lr) >> 6;
        int row = (m0 + lr) & 63;
        int uidx = (row * 64 + col) ^ ((row & 7) << 3);
        aggbf[(size_t)tile * 4096 + uidx] = f2bf((float)hist[i]);
    }
}

// ---------------- fused MFMA (r13/r14/r16 proven: async global_load_lds staging) ----------------
__global__ __launch_bounds__(512) void k_fused(const unsigned short* __restrict__ xbf,
                                               const unsigned short* __restrict__ W1T,
                                               const float* __restrict__ b1,
                                               const unsigned short* __restrict__ W2T,
                                               const float* __restrict__ b2,
                                               const unsigned short* __restrict__ aggbf,
                                               float* __restrict__ out, int N) {
    __shared__ __align__(16) unsigned short xs[64 * 256];
    __shared__ __align__(16) unsigned short as[64 * 64];
    int tid = threadIdx.x;
    int lane = tid & 63;
    int w = tid >> 6;
    int lrow = lane & 15, lkb = lane >> 4;
    int n0 = blockIdx.x * 64;

    {
        const char* xg = (const char*)(xbf + (size_t)blockIdx.x * 16384);
#pragma unroll
        for (int j = 0; j < 4; j++) {
            int ch = w * 4 + j;
            __builtin_amdgcn_global_load_lds(
                (const __attribute__((address_space(1))) unsigned*)(xg + ch * 1024 + lane * 16),
                (__attribute__((address_space(3))) unsigned*)((char*)xs + ch * 1024),
                16, 0, 0);
        }
        const char* ag = (const char*)(aggbf + (size_t)blockIdx.x * 4096);
        __builtin_amdgcn_global_load_lds(
            (const __attribute__((address_space(1))) unsigned*)(ag + w * 1024 + lane * 16),
            (__attribute__((address_space(3))) unsigned*)((char*)as + w * 1024),
            16, 0, 0);
    }
    __syncthreads();

    int wc0 = w * 32;
    floatx4 acc1[4][2];
#pragma unroll
    for (int mt = 0; mt < 4; mt++)
#pragma unroll
        for (int nt = 0; nt < 2; nt++) acc1[mt][nt] = (floatx4){0.f, 0.f, 0.f, 0.f};
    float b1v[2];
#pragma unroll
    for (int nt = 0; nt < 2; nt++) b1v[nt] = b1[wc0 + nt * 16 + lrow];

#pragma unroll
    for (int ks = 0; ks < 8; ks++) {
        int koff = ks * 32 + lkb * 8;
        bhalf8 af[4], bf[2];
#pragma unroll
        for (int mt = 0; mt < 4; mt++) {
            int row = mt * 16 + lrow;
            int uidx = (row * 256 + koff) ^ ((row & 7) << 3);
            af[mt] = *reinterpret_cast<const bhalf8*>(&xs[uidx]);
        }
#pragma unroll
        for (int nt = 0; nt < 2; nt++) {
            int col = wc0 + nt * 16 + lrow;
            bf[nt] = *reinterpret_cast<const bhalf8*>(&W1T[(size_t)col * 256 + koff]);
        }
#pragma unroll
        for (int mt = 0; mt < 4; mt++)
#pragma unroll
            for (int nt = 0; nt < 2; nt++)
                acc1[mt][nt] = __builtin_amdgcn_mfma_f32_16x16x32_bf16(af[mt], bf[nt], acc1[mt][nt], 0, 0, 0);
    }
    __syncthreads();

#pragma unroll
    for (int mt = 0; mt < 4; mt++)
#pragma unroll
        for (int nt = 0; nt < 2; nt++) {
            int col = wc0 + nt * 16 + lrow;
#pragma unroll
            for (int r = 0; r < 4; r++) {
                int row = mt * 16 + lkb * 4 + r;
                float v = fmaxf(acc1[mt][nt][r] + b1v[nt], 0.f);
                int uidx = (row * 256 + col) ^ ((row & 7) << 3);
                xs[uidx] = f2bf(v);
            }
        }
    __syncthreads();

    int r0 = (w >> 1) * 16;
    int odd = w & 1;
    floatx4 acc2[2];
    acc2[0] = (floatx4){0.f, 0.f, 0.f, 0.f};
    acc2[1] = (floatx4){0.f, 0.f, 0.f, 0.f};
    int c0 = odd ? 32 : 0;
#pragma unroll
    for (int ks = 0; ks < 8; ks++) {
        int koff = ks * 32 + lkb * 8;
        int row = r0 + lrow;
        int uidx = (row * 256 + koff) ^ ((row & 7) << 3);
        bhalf8 a = *reinterpret_cast<const bhalf8*>(&xs[uidx]);
        bhalf8 b0 = *reinterpret_cast<const bhalf8*>(&W2T[(size_t)(c0 + lrow) * 320 + koff]);
        acc2[0] = __builtin_amdgcn_mfma_f32_16x16x32_bf16(a, b0, acc2[0], 0, 0, 0);
        if (!odd) {
            bhalf8 b1f = *reinterpret_cast<const bhalf8*>(&W2T[(size_t)(16 + lrow) * 320 + koff]);
            acc2[1] = __builtin_amdgcn_mfma_f32_16x16x32_bf16(a, b1f, acc2[1], 0, 0, 0);
        }
    }
#pragma unroll
    for (int ks = 0; ks < 2; ks++) {
        int koff = ks * 32 + lkb * 8;
        int row = r0 + lrow;
        int uidx = (row * 64 + koff) ^ ((row & 7) << 3);
        bhalf8 a = *reinterpret_cast<const bhalf8*>(&as[uidx]);
        bhalf8 b0 = *reinterpret_cast<const bhalf8*>(&W2T[(size_t)(c0 + lrow) * 320 + 256 + koff]);
        acc2[0] = __builtin_amdgcn_mfma_f32_16x16x32_bf16(a, b0, acc2[0], 0, 0, 0);
        if (!odd) {
            bhalf8 b1f = *reinterpret_cast<const bhalf8*>(&W2T[(size_t)(16 + lrow) * 320 + 256 + koff]);
            acc2[1] = __builtin_amdgcn_mfma_f32_16x16x32_bf16(a, b1f, acc2[1], 0, 0, 0);
        }
    }
    int ntend = odd ? 1 : 2;
#pragma unroll
    for (int nt = 0; nt < 2; nt++) {
        if (nt >= ntend) continue;
        int col = c0 + nt * 16 + lrow;
        if (col >= 40) continue;
        float bb = b2[col];
#pragma unroll
        for (int r = 0; r < 4; r++) {
            int row = n0 + r0 + lkb * 4 + r;
            if (row < N) out[(size_t)row * 40 + col] = acc2[nt][r] + bb;
        }
    }
}

extern "C" void kernel_launch(void* const* d_in, const int* in_sizes, int n_in,
                              void* d_out, int out_size, void* d_ws, size_t ws_size,
                              hipStream_t stream) {
    const float* x  = (const float*)d_in[0];
    const int*   ei = (const int*)d_in[1];
    const int*   ef = (const int*)d_in[2];
    const float* W1 = (const float*)d_in[3];
    const float* b1 = (const float*)d_in[4];
    const float* W2 = (const float*)d_in[5];
    const float* b2 = (const float*)d_in[6];
    float* out = (float*)d_out;

    const int HID = in_sizes[4];            // 256
    const int D   = in_sizes[3] / HID;      // 256
    const int N   = in_sizes[0] / D;        // 100000
    const int E   = in_sizes[1] / 2;        // 3200000
    (void)HID; (void)D;

    const int Escan  = min(N, E);                   // posmin truncation (r19 proof)
    const int nbuck  = (N + BROWS - 1) / BROWS;     // 782
    const int ntiles = (N + 63) / 64;               // 1563
    const int W      = (Escan + 63) / 64;           // 1563 bitmap words
    const int nblk_w = (W + 4096 - 1) / 4096;       // 1

    // workspace layout, 4-byte units (d_ws 16B-aligned); total ~118MB
    int* ws = (int*)d_ws;
    size_t o = 0;
    unsigned short* aggbf = (unsigned short*)(ws + o); o += (size_t)ntiles * 2048;
    int* pos = ws + o;                               o += N;
    int* rank = ws + o;                              o += N;
    int* rt = ws + o;                                o += N;
    int* cursorb = ws + o;                           o += nbuck;
    int* bsum_w = ws + o;                            o += nblk_w + 1;
    o = (o + 1) & ~(size_t)1;                        // 8B align for bitmap
    unsigned long long* bitmap = (unsigned long long*)(ws + o); o += 2 * (size_t)W;
    int* wordpfx = ws + o;                           o += W + 1;
    o = (o + 3) & ~(size_t)3;                        // 16B align
    unsigned* binned = (unsigned*)(ws + o);          o += (size_t)nbuck * BCAP;
    unsigned short* W1T = (unsigned short*)(ws + o); o += 32768;
    unsigned short* W2T = (unsigned short*)(ws + o); o += 7680;
    unsigned short* xbf = (unsigned short*)(ws + o); o += (size_t)ntiles * 8192;

    const int total4 = ntiles * 4096;
    const int nb_x = (total4 + 255) / 256;          // 25008 prep_x blocks
    const int nb_i = (max(max(N, W), nbuck) + 255) / 256;  // 391 init blocks
    const int nb_w = 256;                           // weight-prep blocks (covers 65536 idx)

    hipLaunchKernelGGL(k_preps, dim3(nb_x + nb_i + nb_w), dim3(256), 0, stream,
                       x, xbf, W1, W2, W1T, W2T, pos, cursorb, bitmap,
                       N, total4, nbuck, W, E, nb_x, nb_i);
    hipLaunchKernelGGL(k_posmin, dim3((Escan + 255) / 256), dim3(256), 0, stream, ei, pos, Escan);
    hipLaunchKernelGGL(k_bitmap, dim3((N + 255) / 256), dim3(256), 0, stream, pos, bitmap, N, E);
    hipLaunchKernelGGL(k_bitsum, dim3(nblk_w), dim3(256), 0, stream, bitmap, bsum_w, W);
    hipLaunchKernelGGL(k_scanbsum, dim3(1), dim3(1024), 0, stream, bsum_w, nblk_w);
    hipLaunchKernelGGL(k_wordpfx, dim3(nblk_w), dim3(256), 0, stream, bitmap, bsum_w, wordpfx, W);
    hipLaunchKernelGGL(k_rank_bm, dim3((N + 255) / 256), dim3(256), 0, stream, pos, bitmap, wordpfx, rank, N, E);
    hipLaunchKernelGGL(k_rt, dim3((N + 255) / 256), dim3(256), 0, stream, ei, rank, rt, N);
    hipLaunchKernelGGL(k_mebin, dim3((E + EPB - 1) / EPB), dim3(TPB_MB), 0, stream,
                       ei, rt, ef, cursorb, binned, E, nbuck);
    hipLaunchKernelGGL(k_bgather, dim3(nbuck), dim3(256), 0, stream, cursorb, binned, aggbf, N);
    hipLaunchKernelGGL(k_fused, dim3(ntiles), dim3(512), 0, stream,
                       xbf, W1T, b1, W2T, b2, aggbf, out, N);
}

// Round 22
// 187.466 us; speedup vs baseline: 1.1393x; 1.0096x over previous
//
#include <hip/hip_runtime.h>
#include <hip/hip_bf16.h>

#define WCHUNK 16   // bitmap words per thread in scan kernels
#define EPB  8192   // edges per k_mebin block
#define TPB_MB 1024 // r22: 16 waves/block for latency cover (bounds(1024,4) keeps VGPR)
#define BROWS 128   // rank-rows per bucket
#define BCAP 16384  // entry capacity per bucket (early buckets size-biased to ~8300
                    // mean; 8192 overflowed (r5/r6); 16384 ≈ 15σ)

typedef __attribute__((ext_vector_type(8))) short bhalf8;
typedef __attribute__((ext_vector_type(4))) float floatx4;

__device__ __forceinline__ unsigned short f2bf(float f) {
    __hip_bfloat16 h = __float2bfloat16(f);     // native RNE
    union { __hip_bfloat16 h; unsigned short u; } v;
    v.h = h;
    return v.u;
}

// ---------------- merged prep: xbf tiles | init pos/cursorb/bitmap | W1T/W2T (proven r17) ----------------
__global__ void k_preps(const float* __restrict__ x, unsigned short* __restrict__ xbf,
                        const float* __restrict__ W1, const float* __restrict__ W2,
                        unsigned short* __restrict__ W1T, unsigned short* __restrict__ W2T,
                        int* __restrict__ pos, int* __restrict__ cursorb,
                        unsigned long long* __restrict__ bitmap,
                        int N, int total4, int nbuck, int W, int E, int nb_x, int nb_i) {
    int bid = blockIdx.x;
    int tid = threadIdx.x;
    if (bid < nb_x) {
        // ---- prep_x: f32 -> bf16, tile-major, XOR-pre-swizzled, zero-padded ----
        int f = bid * 256 + tid;
        if (f >= total4) return;
        int tile = f >> 12;
        int row = (f >> 6) & 63;
        int c4 = (f & 63) * 4;
        int grow = tile * 64 + row;
        float4 v = (grow < N) ? *reinterpret_cast<const float4*>(x + (size_t)grow * 256 + c4)
                              : make_float4(0.f, 0.f, 0.f, 0.f);
        ushort4 bv;
        bv.x = f2bf(v.x); bv.y = f2bf(v.y); bv.z = f2bf(v.z); bv.w = f2bf(v.w);
        int uidx = (row * 256 + c4) ^ ((row & 7) << 3);
        *reinterpret_cast<ushort4*>(&xbf[(size_t)tile * 16384 + uidx]) = bv;
    } else if (bid < nb_x + nb_i) {
        // ---- init: pos = E; cursorb[b] = b*BCAP; bitmap = 0 ----
        int i = (bid - nb_x) * 256 + tid;
        if (i < N) pos[i] = E;
        if (i < nbuck) cursorb[i] = i * BCAP;
        if (i < W) bitmap[i] = 0ull;
    } else {
        // ---- prep: W1T/W2T bf16 transposed weights ----
        int i = (bid - nb_x - nb_i) * 256 + tid;
        if (i < 256 * 256) {
            int c = i >> 8, k = i & 255;
            W1T[i] = f2bf(W1[k * 256 + c]);     // W1T[c][k] = W1[k][c]
        }
        if (i < 48 * 320) {
            int c = i / 320, k = i % 320;
            W2T[i] = (c < 40) ? f2bf(W2[k * 40 + c]) : (unsigned short)0;
        }
    }
}

// ---------------- posmin over the FIRST Escan=min(N,E) edges only (proven r19) ----------------
__global__ void k_posmin(const int* __restrict__ ei, int* __restrict__ pos, int Escan) {
    int e = blockIdx.x * blockDim.x + threadIdx.x;
    if (e < Escan) {
        int s = ((const int2*)ei)[e].x;
        if (pos[s] > e) atomicMin(&pos[s], e);
    }
}

// ---------------- bitmap: set bit pos[n] for found nodes (proven) ----------------
__global__ void k_bitmap(const int* __restrict__ pos, unsigned long long* __restrict__ bitmap,
                         int N, int E) {
    int n = blockIdx.x * blockDim.x + threadIdx.x;
    if (n < N) {
        int p = pos[n];
        if (p < E) atomicOr(&bitmap[p >> 6], 1ull << (p & 63));
    }
}

// ---------------- per-block popcount sums over bitmap (proven r16) ----------------
__global__ void k_bitsum(const unsigned long long* __restrict__ bitmap,
                         int* __restrict__ bsum, int W) {
    __shared__ int sdata[256];
    int t = threadIdx.x;
    int base = (blockIdx.x * 256 + t) * WCHUNK;
    int cnt = 0;
    for (int l = 0; l < WCHUNK; l++) {
        int i = base + l;
        if (i < W) cnt += __popcll(bitmap[i]);
    }
    sdata[t] = cnt;
    __syncthreads();
    for (int s = 128; s > 0; s >>= 1) {
        if (t < s) sdata[t] += sdata[t + s];
        __syncthreads();
    }
    if (t == 0) bsum[blockIdx.x] = sdata[0];
}

// ---------------- exclusive scan of block sums (proven; nblk tiny) ----------------
__global__ void k_scanbsum(int* __restrict__ bsum, int nblk) {
    __shared__ int part[1024];
    const int T = 1024;
    int t = threadIdx.x;
    int per = (nblk + T - 1) / T;
    int s0 = t * per, s1 = min(s0 + per, nblk);
    int sum = 0;
    for (int i = s0; i < s1; i++) sum += bsum[i];
    part[t] = sum;
    __syncthreads();
    for (int off = 1; off < T; off <<= 1) {
        int v = 0;
        if (t >= off) v = part[t - off];
        __syncthreads();
        part[t] += v;
        __syncthreads();
    }
    int run = part[t] - sum;
    for (int i = s0; i < s1; i++) {
        int old = bsum[i];
        bsum[i] = run;
        run += old;
    }
    if (t == T - 1) bsum[nblk] = part[T - 1];
}

// ---------------- per-word exclusive popcount prefix (proven r16) ----------------
__global__ void k_wordpfx(const unsigned long long* __restrict__ bitmap,
                          const int* __restrict__ bsum, int* __restrict__ wordpfx, int W) {
    __shared__ int sdata[256];
    int t = threadIdx.x;
    int base = (blockIdx.x * 256 + t) * WCHUNK;
    int cnt = 0;
    for (int l = 0; l < WCHUNK; l++) {
        int i = base + l;
        if (i < W) cnt += __popcll(bitmap[i]);
    }
    sdata[t] = cnt;
    __syncthreads();
    for (int off = 1; off < 256; off <<= 1) {
        int v = 0;
        if (t >= off) v = sdata[t - off];
        __syncthreads();
        sdata[t] += v;
        __syncthreads();
    }
    int run = bsum[blockIdx.x] + sdata[t] - cnt;   // exclusive start for this thread
    for (int l = 0; l < WCHUNK; l++) {
        int i = base + l;
        if (i >= W) break;
        wordpfx[i] = run;
        run += __popcll(bitmap[i]);
    }
}

// ---------------- rt[n] = bitmapRank(pos[seg[n]]) -- merged r21 rank_bm + rt ----------------
// Valid: for n < N, seg[n] is present (pos[seg[n]] <= n < N < E). Same math as
// rank_bm applied at pos[seg[n]]; removes the rank[] intermediate and one launch.
__global__ void k_rt(const int* __restrict__ ei, const int* __restrict__ pos,
                     const unsigned long long* __restrict__ bitmap,
                     const int* __restrict__ wordpfx, int* __restrict__ rt, int N) {
    int n = blockIdx.x * blockDim.x + threadIdx.x;
    if (n >= N) return;
    int sn = ((const int2*)ei)[n].x;
    int p = pos[sn];
    int w = p >> 6, off = p & 63;
    unsigned long long mask = (1ull << off) - 1ull;
    rt[n] = wordpfx[w] + __popcll(bitmap[w] & mask);
}

// ---------------- mebin: gather + bucket binning, LDS-staged ----------------
// r22: TPB 1024 (16 waves/block -> ~24 waves/CU at 391 blocks; r21 had 8 -> 26% occ).
// bounds(1024,4) guarantees a fat VGPR budget (r13's no-bounds 1024-thr got 8 VGPRs).
__global__ __launch_bounds__(TPB_MB, 4) void k_mebin(const int* __restrict__ ei,
                                                     const int* __restrict__ rt,
                                                     const int* __restrict__ ef,
                                                     int* __restrict__ cursorb,
                                                     unsigned* __restrict__ binned,
                                                     int E, int nbuck) {
    __shared__ unsigned lmp[EPB];          // 32KB: (m<<16)|pv per staged edge
    __shared__ int lcnt[800];
    __shared__ int lbase[800];
    __shared__ int lfill[800];
    int tid = threadIdx.x;
    int base = blockIdx.x * EPB;
    for (int b = tid; b < nbuck; b += TPB_MB) { lcnt[b] = 0; lfill[b] = 0; }
    __syncthreads();
    // gather + stage + count: 8 edges/thread in 2 batches of 4 independent chains
#pragma unroll
    for (int jj = 0; jj < 2; jj++) {
        int l0 = (jj * 4 + 0) * TPB_MB + tid;
        int l1 = (jj * 4 + 1) * TPB_MB + tid;
        int l2 = (jj * 4 + 2) * TPB_MB + tid;
        int l3 = (jj * 4 + 3) * TPB_MB + tid;
        int e0 = base + l0, e1 = base + l1, e2 = base + l2, e3 = base + l3;
        int s0 = 0, s1 = 0, s2 = 0, s3 = 0;
        if (e0 < E) s0 = ((const int2*)ei)[e0].x;
        if (e1 < E) s1 = ((const int2*)ei)[e1].x;
        if (e2 < E) s2 = ((const int2*)ei)[e2].x;
        if (e3 < E) s3 = ((const int2*)ei)[e3].x;
        int m0 = 0, m1 = 0, m2 = 0, m3 = 0;
        if (e0 < E) m0 = rt[s0];
        if (e1 < E) m1 = rt[s1];
        if (e2 < E) m2 = rt[s2];
        if (e3 < E) m3 = rt[s3];
        int4 f0, f1, f2, f3;
        if (e0 < E) f0 = *reinterpret_cast<const int4*>(ef + 4 * (size_t)e0);
        if (e1 < E) f1 = *reinterpret_cast<const int4*>(ef + 4 * (size_t)e1);
        if (e2 < E) f2 = *reinterpret_cast<const int4*>(ef + 4 * (size_t)e2);
        if (e3 < E) f3 = *reinterpret_cast<const int4*>(ef + 4 * (size_t)e3);
        if (e0 < E) { lmp[l0] = ((unsigned)m0 << 16) | (unsigned)(f0.x | (f0.y << 4) | (f0.z << 8) | (f0.w << 12)); atomicAdd(&lcnt[m0 >> 7], 1); }
        if (e1 < E) { lmp[l1] = ((unsigned)m1 << 16) | (unsigned)(f1.x | (f1.y << 4) | (f1.z << 8) | (f1.w << 12)); atomicAdd(&lcnt[m1 >> 7], 1); }
        if (e2 < E) { lmp[l2] = ((unsigned)m2 << 16) | (unsigned)(f2.x | (f2.y << 4) | (f2.z << 8) | (f2.w << 12)); atomicAdd(&lcnt[m2 >> 7], 1); }
        if (e3 < E) { lmp[l3] = ((unsigned)m3 << 16) | (unsigned)(f3.x | (f3.y << 4) | (f3.z << 8) | (f3.w << 12)); atomicAdd(&lcnt[m3 >> 7], 1); }
    }
    __syncthreads();
    // claim contiguous global runs per bucket
    for (int b = tid; b < nbuck; b += TPB_MB) {
        int c = lcnt[b];
        lbase[b] = (c > 0) ? atomicAdd(&cursorb[b], c) : 0;
    }
    __syncthreads();
    // write from LDS only
#pragma unroll
    for (int j = 0; j < EPB / TPB_MB; j++) {
        int li = j * TPB_MB + tid;
        if (base + li < E) {
            unsigned v = lmp[li];
            int b = v >> 23;
            int off = atomicAdd(&lfill[b], 1);
            long long slot = (long long)lbase[b] + off;
            if (slot < (long long)(b + 1) * BCAP)   // overflow guard
                binned[slot] = v & 0x7FFFFFu;       // (m&127)<<16 | pv
        }
    }
}

// ---------------- bucket gather: LDS histogram -> bf16 pre-swizzled agg tiles (proven) ----------------
__global__ __launch_bounds__(256) void k_bgather(const int* __restrict__ cursorb,
                                                 const unsigned* __restrict__ binned,
                                                 unsigned short* __restrict__ aggbf, int N) {
    __shared__ int hist[BROWS * 64];   // 32KB
    int tid = threadIdx.x;
    int b = blockIdx.x;
    int m0 = b * BROWS;
    for (int i = tid; i < BROWS * 64; i += 256) hist[i] = 0;
    __syncthreads();
    int r0 = b * BCAP;
    int r1 = min(cursorb[b], (b + 1) * BCAP);
    for (int i = r0 + tid; i < r1; i += 256) {
        unsigned v = binned[i];
        int lr = (int)(v >> 16) << 6;           // local row (m&127) * 64
        atomicAdd(&hist[lr + (v & 15u)], 1);
        atomicAdd(&hist[lr + 16 + ((v >> 4) & 15u)], 1);
        atomicAdd(&hist[lr + 32 + ((v >> 8) & 15u)], 1);
        atomicAdd(&hist[lr + 48 + ((v >> 12) & 15u)], 1);
    }
    __syncthreads();
    int rows = min(BROWS, N - m0);
    for (int i = tid; i < rows * 64; i += 256) {
        int lr = i >> 6, col = i & 63;
        int tile = (m0 + lr) >> 6;
        int row = (m0 + lr) & 63;
        int uidx = (row * 64 + col) ^ ((row & 7) << 3);
        aggbf[(size_t)tile * 4096 + uidx] = f2bf((float)hist[i]);
    }
}

// ---------------- fused MFMA (r13/r14/r16 proven: async global_load_lds staging) ----------------
__global__ __launch_bounds__(512) void k_fused(const unsigned short* __restrict__ xbf,
                                               const unsigned short* __restrict__ W1T,
                                               const float* __restrict__ b1,
                                               const unsigned short* __restrict__ W2T,
                                               const float* __restrict__ b2,
                                               const unsigned short* __restrict__ aggbf,
                                               float* __restrict__ out, int N) {
    __shared__ __align__(16) unsigned short xs[64 * 256];
    __shared__ __align__(16) unsigned short as[64 * 64];
    int tid = threadIdx.x;
    int lane = tid & 63;
    int w = tid >> 6;
    int lrow = lane & 15, lkb = lane >> 4;
    int n0 = blockIdx.x * 64;

    {
        const char* xg = (const char*)(xbf + (size_t)blockIdx.x * 16384);
#pragma unroll
        for (int j = 0; j < 4; j++) {
            int ch = w * 4 + j;
            __builtin_amdgcn_global_load_lds(
                (const __attribute__((address_space(1))) unsigned*)(xg + ch * 1024 + lane * 16),
                (__attribute__((address_space(3))) unsigned*)((char*)xs + ch * 1024),
                16, 0, 0);
        }
        const char* ag = (const char*)(aggbf + (size_t)blockIdx.x * 4096);
        __builtin_amdgcn_global_load_lds(
            (const __attribute__((address_space(1))) unsigned*)(ag + w * 1024 + lane * 16),
            (__attribute__((address_space(3))) unsigned*)((char*)as + w * 1024),
            16, 0, 0);
    }
    __syncthreads();

    int wc0 = w * 32;
    floatx4 acc1[4][2];
#pragma unroll
    for (int mt = 0; mt < 4; mt++)
#pragma unroll
        for (int nt = 0; nt < 2; nt++) acc1[mt][nt] = (floatx4){0.f, 0.f, 0.f, 0.f};
    float b1v[2];
#pragma unroll
    for (int nt = 0; nt < 2; nt++) b1v[nt] = b1[wc0 + nt * 16 + lrow];

#pragma unroll
    for (int ks = 0; ks < 8; ks++) {
        int koff = ks * 32 + lkb * 8;
        bhalf8 af[4], bf[2];
#pragma unroll
        for (int mt = 0; mt < 4; mt++) {
            int row = mt * 16 + lrow;
            int uidx = (row * 256 + koff) ^ ((row & 7) << 3);
            af[mt] = *reinterpret_cast<const bhalf8*>(&xs[uidx]);
        }
#pragma unroll
        for (int nt = 0; nt < 2; nt++) {
            int col = wc0 + nt * 16 + lrow;
            bf[nt] = *reinterpret_cast<const bhalf8*>(&W1T[(size_t)col * 256 + koff]);
        }
#pragma unroll
        for (int mt = 0; mt < 4; mt++)
#pragma unroll
            for (int nt = 0; nt < 2; nt++)
                acc1[mt][nt] = __builtin_amdgcn_mfma_f32_16x16x32_bf16(af[mt], bf[nt], acc1[mt][nt], 0, 0, 0);
    }
    __syncthreads();

#pragma unroll
    for (int mt = 0; mt < 4; mt++)
#pragma unroll
        for (int nt = 0; nt < 2; nt++) {
            int col = wc0 + nt * 16 + lrow;
#pragma unroll
            for (int r = 0; r < 4; r++) {
                int row = mt * 16 + lkb * 4 + r;
                float v = fmaxf(acc1[mt][nt][r] + b1v[nt], 0.f);
                int uidx = (row * 256 + col) ^ ((row & 7) << 3);
                xs[uidx] = f2bf(v);
            }
        }
    __syncthreads();

    int r0 = (w >> 1) * 16;
    int odd = w & 1;
    floatx4 acc2[2];
    acc2[0] = (floatx4){0.f, 0.f, 0.f, 0.f};
    acc2[1] = (floatx4){0.f, 0.f, 0.f, 0.f};
    int c0 = odd ? 32 : 0;
#pragma unroll
    for (int ks = 0; ks < 8; ks++) {
        int koff = ks * 32 + lkb * 8;
        int row = r0 + lrow;
        int uidx = (row * 256 + koff) ^ ((row & 7) << 3);
        bhalf8 a = *reinterpret_cast<const bhalf8*>(&xs[uidx]);
        bhalf8 b0 = *reinterpret_cast<const bhalf8*>(&W2T[(size_t)(c0 + lrow) * 320 + koff]);
        acc2[0] = __builtin_amdgcn_mfma_f32_16x16x32_bf16(a, b0, acc2[0], 0, 0, 0);
        if (!odd) {
            bhalf8 b1f = *reinterpret_cast<const bhalf8*>(&W2T[(size_t)(16 + lrow) * 320 + koff]);
            acc2[1] = __builtin_amdgcn_mfma_f32_16x16x32_bf16(a, b1f, acc2[1], 0, 0, 0);
        }
    }
#pragma unroll
    for (int ks = 0; ks < 2; ks++) {
        int koff = ks * 32 + lkb * 8;
        int row = r0 + lrow;
        int uidx = (row * 64 + koff) ^ ((row & 7) << 3);
        bhalf8 a = *reinterpret_cast<const bhalf8*>(&as[uidx]);
        bhalf8 b0 = *reinterpret_cast<const bhalf8*>(&W2T[(size_t)(c0 + lrow) * 320 + 256 + koff]);
        acc2[0] = __builtin_amdgcn_mfma_f32_16x16x32_bf16(a, b0, acc2[0], 0, 0, 0);
        if (!odd) {
            bhalf8 b1f = *reinterpret_cast<const bhalf8*>(&W2T[(size_t)(16 + lrow) * 320 + 256 + koff]);
            acc2[1] = __builtin_amdgcn_mfma_f32_16x16x32_bf16(a, b1f, acc2[1], 0, 0, 0);
        }
    }
    int ntend = odd ? 1 : 2;
#pragma unroll
    for (int nt = 0; nt < 2; nt++) {
        if (nt >= ntend) continue;
        int col = c0 + nt * 16 + lrow;
        if (col >= 40) continue;
        float bb = b2[col];
#pragma unroll
        for (int r = 0; r < 4; r++) {
            int row = n0 + r0 + lkb * 4 + r;
            if (row < N) out[(size_t)row * 40 + col] = acc2[nt][r] + bb;
        }
    }
}

extern "C" void kernel_launch(void* const* d_in, const int* in_sizes, int n_in,
                              void* d_out, int out_size, void* d_ws, size_t ws_size,
                              hipStream_t stream) {
    const float* x  = (const float*)d_in[0];
    const int*   ei = (const int*)d_in[1];
    const int*   ef = (const int*)d_in[2];
    const float* W1 = (const float*)d_in[3];
    const float* b1 = (const float*)d_in[4];
    const float* W2 = (const float*)d_in[5];
    const float* b2 = (const float*)d_in[6];
    float* out = (float*)d_out;

    const int HID = in_sizes[4];            // 256
    const int D   = in_sizes[3] / HID;      // 256
    const int N   = in_sizes[0] / D;        // 100000
    const int E   = in_sizes[1] / 2;        // 3200000
    (void)HID; (void)D;

    const int Escan  = min(N, E);                   // posmin truncation (r19 proof)
    const int nbuck  = (N + BROWS - 1) / BROWS;     // 782
    const int ntiles = (N + 63) / 64;               // 1563
    const int W      = (Escan + 63) / 64;           // 1563 bitmap words
    const int nblk_w = (W + 4096 - 1) / 4096;       // 1

    // workspace layout, 4-byte units (d_ws 16B-aligned); total ~118MB
    int* ws = (int*)d_ws;
    size_t o = 0;
    unsigned short* aggbf = (unsigned short*)(ws + o); o += (size_t)ntiles * 2048;
    int* pos = ws + o;                               o += N;
    int* rt = ws + o;                                o += N;
    int* cursorb = ws + o;                           o += nbuck;
    int* bsum_w = ws + o;                            o += nblk_w + 1;
    o = (o + 1) & ~(size_t)1;                        // 8B align for bitmap
    unsigned long long* bitmap = (unsigned long long*)(ws + o); o += 2 * (size_t)W;
    int* wordpfx = ws + o;                           o += W + 1;
    o = (o + 3) & ~(size_t)3;                        // 16B align
    unsigned* binned = (unsigned*)(ws + o);          o += (size_t)nbuck * BCAP;
    unsigned short* W1T = (unsigned short*)(ws + o); o += 32768;
    unsigned short* W2T = (unsigned short*)(ws + o); o += 7680;
    unsigned short* xbf = (unsigned short*)(ws + o); o += (size_t)ntiles * 8192;

    const int total4 = ntiles * 4096;
    const int nb_x = (total4 + 255) / 256;          // 25008 prep_x blocks
    const int nb_i = (max(max(N, W), nbuck) + 255) / 256;  // 391 init blocks
    const int nb_w = 256;                           // weight-prep blocks (covers 65536 idx)

    hipLaunchKernelGGL(k_preps, dim3(nb_x + nb_i + nb_w), dim3(256), 0, stream,
                       x, xbf, W1, W2, W1T, W2T, pos, cursorb, bitmap,
                       N, total4, nbuck, W, E, nb_x, nb_i);
    hipLaunchKernelGGL(k_posmin, dim3((Escan + 255) / 256), dim3(256), 0, stream, ei, pos, Escan);
    hipLaunchKernelGGL(k_bitmap, dim3((N + 255) / 256), dim3(256), 0, stream, pos, bitmap, N, E);
    hipLaunchKernelGGL(k_bitsum, dim3(nblk_w), dim3(256), 0, stream, bitmap, bsum_w, W);
    hipLaunchKernelGGL(k_scanbsum, dim3(1), dim3(1024), 0, stream, bsum_w, nblk_w);
    hipLaunchKernelGGL(k_wordpfx, dim3(nblk_w), dim3(256), 0, stream, bitmap, bsum_w, wordpfx, W);
    hipLaunchKernelGGL(k_rt, dim3((N + 255) / 256), dim3(256), 0, stream, ei, pos, bitmap, wordpfx, rt, N);
    hipLaunchKernelGGL(k_mebin, dim3((E + EPB - 1) / EPB), dim3(TPB_MB), 0, stream,
                       ei, rt, ef, cursorb, binned, E, nbuck);
    hipLaunchKernelGGL(k_bgather, dim3(nbuck), dim3(256), 0, stream, cursorb, binned, aggbf, N);
    hipLaunchKernelGGL(k_fused, dim3(ntiles), dim3(512), 0, stream,
                       xbf, W1T, b1, W2T, b2, aggbf, out, N);
}

// Round 23
// 176.933 us; speedup vs baseline: 1.2071x; 1.0595x over previous
//
#include <hip/hip_runtime.h>
#include <hip/hip_bf16.h>

#define EPB  8192   // edges per k_mebin block
#define TPB_MB 1024 // 16 waves/block (r22)
#define BROWS 128   // rank-rows per bucket
#define BCAP 16384  // entry capacity per bucket (early buckets size-biased to ~8300
                    // mean; 8192 overflowed (r5/r6); 16384 ≈ 15σ)

typedef __attribute__((ext_vector_type(8))) short bhalf8;
typedef __attribute__((ext_vector_type(4))) float floatx4;

__device__ __forceinline__ unsigned short f2bf(float f) {
    __hip_bfloat16 h = __float2bfloat16(f);     // native RNE
    union { __hip_bfloat16 h; unsigned short u; } v;
    v.h = h;
    return v.u;
}

// ---------------- merged prep: xbf tiles | init pos/cursorb/bitmap | W1T/W2T ----------------
// r23: prep_x section handles 2 float4/thread (512 per block).
__global__ void k_preps(const float* __restrict__ x, unsigned short* __restrict__ xbf,
                        const float* __restrict__ W1, const float* __restrict__ W2,
                        unsigned short* __restrict__ W1T, unsigned short* __restrict__ W2T,
                        int* __restrict__ pos, int* __restrict__ cursorb,
                        unsigned long long* __restrict__ bitmap,
                        int N, int total4, int nbuck, int W, int E, int nb_x, int nb_i) {
    int bid = blockIdx.x;
    int tid = threadIdx.x;
    if (bid < nb_x) {
        // ---- prep_x: f32 -> bf16, tile-major, XOR-pre-swizzled, zero-padded ----
#pragma unroll
        for (int j = 0; j < 2; j++) {
            int f = bid * 512 + j * 256 + tid;
            if (f >= total4) continue;
            int tile = f >> 12;
            int row = (f >> 6) & 63;
            int c4 = (f & 63) * 4;
            int grow = tile * 64 + row;
            float4 v = (grow < N) ? *reinterpret_cast<const float4*>(x + (size_t)grow * 256 + c4)
                                  : make_float4(0.f, 0.f, 0.f, 0.f);
            ushort4 bv;
            bv.x = f2bf(v.x); bv.y = f2bf(v.y); bv.z = f2bf(v.z); bv.w = f2bf(v.w);
            int uidx = (row * 256 + c4) ^ ((row & 7) << 3);
            *reinterpret_cast<ushort4*>(&xbf[(size_t)tile * 16384 + uidx]) = bv;
        }
    } else if (bid < nb_x + nb_i) {
        // ---- init: pos = E; cursorb[b] = b*BCAP; bitmap = 0 ----
        int i = (bid - nb_x) * 256 + tid;
        if (i < N) pos[i] = E;
        if (i < nbuck) cursorb[i] = i * BCAP;
        if (i < W) bitmap[i] = 0ull;
    } else {
        // ---- prep: W1T/W2T bf16 transposed weights ----
        int i = (bid - nb_x - nb_i) * 256 + tid;
        if (i < 256 * 256) {
            int c = i >> 8, k = i & 255;
            W1T[i] = f2bf(W1[k * 256 + c]);     // W1T[c][k] = W1[k][c]
        }
        if (i < 48 * 320) {
            int c = i / 320, k = i % 320;
            W2T[i] = (c < 40) ? f2bf(W2[k * 40 + c]) : (unsigned short)0;
        }
    }
}

// ---------------- posmin over the FIRST Escan=min(N,E) edges only (proven r19) ----------------
__global__ void k_posmin(const int* __restrict__ ei, int* __restrict__ pos, int Escan) {
    int e = blockIdx.x * blockDim.x + threadIdx.x;
    if (e < Escan) {
        int s = ((const int2*)ei)[e].x;
        if (pos[s] > e) atomicMin(&pos[s], e);
    }
}

// ---------------- bitmap: set bit pos[n] for found nodes (proven) ----------------
__global__ void k_bitmap(const int* __restrict__ pos, unsigned long long* __restrict__ bitmap,
                         int N, int E) {
    int n = blockIdx.x * blockDim.x + threadIdx.x;
    if (n < N) {
        int p = pos[n];
        if (p < E) atomicOr(&bitmap[p >> 6], 1ull << (p & 63));
    }
}

// ---------------- single-block popcount-prefix over W<=~4K words ----------------
// r23: replaces bitsum+scanbsum+wordpfx (3 launches). Safe at W=1563 (~1.5
// words/thread) — r15's single-block failure was W=50000.
__global__ void k_scanw(const unsigned long long* __restrict__ bitmap,
                        int* __restrict__ wordpfx, int W) {
    __shared__ int part[1024];
    const int T = 1024;
    int t = threadIdx.x;
    int per = (W + T - 1) / T;
    int s0 = t * per, s1 = min(s0 + per, W);
    int sum = 0;
    for (int i = s0; i < s1; i++) sum += __popcll(bitmap[i]);
    part[t] = sum;
    __syncthreads();
    for (int off = 1; off < T; off <<= 1) {
        int v = 0;
        if (t >= off) v = part[t - off];
        __syncthreads();
        part[t] += v;
        __syncthreads();
    }
    int run = part[t] - sum;       // exclusive prefix for this thread's chunk
    for (int i = s0; i < s1; i++) {
        wordpfx[i] = run;
        run += __popcll(bitmap[i]);
    }
    if (t == T - 1) wordpfx[W] = part[T - 1];
}

// ---------------- rt[n] = bitmapRank(pos[seg[n]]) (proven r22) ----------------
__global__ void k_rt(const int* __restrict__ ei, const int* __restrict__ pos,
                     const unsigned long long* __restrict__ bitmap,
                     const int* __restrict__ wordpfx, int* __restrict__ rt, int N) {
    int n = blockIdx.x * blockDim.x + threadIdx.x;
    if (n >= N) return;
    int sn = ((const int2*)ei)[n].x;
    int p = pos[sn];
    int w = p >> 6, off = p & 63;
    unsigned long long mask = (1ull << off) - 1ull;
    rt[n] = wordpfx[w] + __popcll(bitmap[w] & mask);
}

// ---------------- mebin: gather + bucket binning, LDS-staged (proven r22) ----------------
__global__ __launch_bounds__(TPB_MB, 4) void k_mebin(const int* __restrict__ ei,
                                                     const int* __restrict__ rt,
                                                     const int* __restrict__ ef,
                                                     int* __restrict__ cursorb,
                                                     unsigned* __restrict__ binned,
                                                     int E, int nbuck) {
    __shared__ unsigned lmp[EPB];          // 32KB: (m<<16)|pv per staged edge
    __shared__ int lcnt[800];
    __shared__ int lbase[800];
    __shared__ int lfill[800];
    int tid = threadIdx.x;
    int base = blockIdx.x * EPB;
    for (int b = tid; b < nbuck; b += TPB_MB) { lcnt[b] = 0; lfill[b] = 0; }
    __syncthreads();
    // gather + stage + count: 8 edges/thread in 2 batches of 4 independent chains
#pragma unroll
    for (int jj = 0; jj < 2; jj++) {
        int l0 = (jj * 4 + 0) * TPB_MB + tid;
        int l1 = (jj * 4 + 1) * TPB_MB + tid;
        int l2 = (jj * 4 + 2) * TPB_MB + tid;
        int l3 = (jj * 4 + 3) * TPB_MB + tid;
        int e0 = base + l0, e1 = base + l1, e2 = base + l2, e3 = base + l3;
        int s0 = 0, s1 = 0, s2 = 0, s3 = 0;
        if (e0 < E) s0 = ((const int2*)ei)[e0].x;
        if (e1 < E) s1 = ((const int2*)ei)[e1].x;
        if (e2 < E) s2 = ((const int2*)ei)[e2].x;
        if (e3 < E) s3 = ((const int2*)ei)[e3].x;
        int m0 = 0, m1 = 0, m2 = 0, m3 = 0;
        if (e0 < E) m0 = rt[s0];
        if (e1 < E) m1 = rt[s1];
        if (e2 < E) m2 = rt[s2];
        if (e3 < E) m3 = rt[s3];
        int4 f0, f1, f2, f3;
        if (e0 < E) f0 = *reinterpret_cast<const int4*>(ef + 4 * (size_t)e0);
        if (e1 < E) f1 = *reinterpret_cast<const int4*>(ef + 4 * (size_t)e1);
        if (e2 < E) f2 = *reinterpret_cast<const int4*>(ef + 4 * (size_t)e2);
        if (e3 < E) f3 = *reinterpret_cast<const int4*>(ef + 4 * (size_t)e3);
        if (e0 < E) { lmp[l0] = ((unsigned)m0 << 16) | (unsigned)(f0.x | (f0.y << 4) | (f0.z << 8) | (f0.w << 12)); atomicAdd(&lcnt[m0 >> 7], 1); }
        if (e1 < E) { lmp[l1] = ((unsigned)m1 << 16) | (unsigned)(f1.x | (f1.y << 4) | (f1.z << 8) | (f1.w << 12)); atomicAdd(&lcnt[m1 >> 7], 1); }
        if (e2 < E) { lmp[l2] = ((unsigned)m2 << 16) | (unsigned)(f2.x | (f2.y << 4) | (f2.z << 8) | (f2.w << 12)); atomicAdd(&lcnt[m2 >> 7], 1); }
        if (e3 < E) { lmp[l3] = ((unsigned)m3 << 16) | (unsigned)(f3.x | (f3.y << 4) | (f3.z << 8) | (f3.w << 12)); atomicAdd(&lcnt[m3 >> 7], 1); }
    }
    __syncthreads();
    // claim contiguous global runs per bucket
    for (int b = tid; b < nbuck; b += TPB_MB) {
        int c = lcnt[b];
        lbase[b] = (c > 0) ? atomicAdd(&cursorb[b], c) : 0;
    }
    __syncthreads();
    // write from LDS only
#pragma unroll
    for (int j = 0; j < EPB / TPB_MB; j++) {
        int li = j * TPB_MB + tid;
        if (base + li < E) {
            unsigned v = lmp[li];
            int b = v >> 23;
            int off = atomicAdd(&lfill[b], 1);
            long long slot = (long long)lbase[b] + off;
            if (slot < (long long)(b + 1) * BCAP)   // overflow guard
                binned[slot] = v & 0x7FFFFFu;       // (m&127)<<16 | pv
        }
    }
}

// ---------------- bucket gather: LDS histogram -> bf16 pre-swizzled agg tiles (proven) ----------------
__global__ __launch_bounds__(256) void k_bgather(const int* __restrict__ cursorb,
                                                 const unsigned* __restrict__ binned,
                                                 unsigned short* __restrict__ aggbf, int N) {
    __shared__ int hist[BROWS * 64];   // 32KB
    int tid = threadIdx.x;
    int b = blockIdx.x;
    int m0 = b * BROWS;
    for (int i = tid; i < BROWS * 64; i += 256) hist[i] = 0;
    __syncthreads();
    int r0 = b * BCAP;
    int r1 = min(cursorb[b], (b + 1) * BCAP);
    for (int i = r0 + tid; i < r1; i += 256) {
        unsigned v = binned[i];
        int lr = (int)(v >> 16) << 6;           // local row (m&127) * 64
        atomicAdd(&hist[lr + (v & 15u)], 1);
        atomicAdd(&hist[lr + 16 + ((v >> 4) & 15u)], 1);
        atomicAdd(&hist[lr + 32 + ((v >> 8) & 15u)], 1);
        atomicAdd(&hist[lr + 48 + ((v >> 12) & 15u)], 1);
    }
    __syncthreads();
    int rows = min(BROWS, N - m0);
    for (int i = tid; i < rows * 64; i += 256) {
        int lr = i >> 6, col = i & 63;
        int tile = (m0 + lr) >> 6;
        int row = (m0 + lr) & 63;
        int uidx = (row * 64 + col) ^ ((row & 7) << 3);
        aggbf[(size_t)tile * 4096 + uidx] = f2bf((float)hist[i]);
    }
}

// ---------------- fused MFMA (r13/r14/r16 proven: async global_load_lds staging) ----------------
__global__ __launch_bounds__(512) void k_fused(const unsigned short* __restrict__ xbf,
                                               const unsigned short* __restrict__ W1T,
                                               const float* __restrict__ b1,
                                               const unsigned short* __restrict__ W2T,
                                               const float* __restrict__ b2,
                                               const unsigned short* __restrict__ aggbf,
                                               float* __restrict__ out, int N) {
    __shared__ __align__(16) unsigned short xs[64 * 256];
    __shared__ __align__(16) unsigned short as[64 * 64];
    int tid = threadIdx.x;
    int lane = tid & 63;
    int w = tid >> 6;
    int lrow = lane & 15, lkb = lane >> 4;
    int n0 = blockIdx.x * 64;

    {
        const char* xg = (const char*)(xbf + (size_t)blockIdx.x * 16384);
#pragma unroll
        for (int j = 0; j < 4; j++) {
            int ch = w * 4 + j;
            __builtin_amdgcn_global_load_lds(
                (const __attribute__((address_space(1))) unsigned*)(xg + ch * 1024 + lane * 16),
                (__attribute__((address_space(3))) unsigned*)((char*)xs + ch * 1024),
                16, 0, 0);
        }
        const char* ag = (const char*)(aggbf + (size_t)blockIdx.x * 4096);
        __builtin_amdgcn_global_load_lds(
            (const __attribute__((address_space(1))) unsigned*)(ag + w * 1024 + lane * 16),
            (__attribute__((address_space(3))) unsigned*)((char*)as + w * 1024),
            16, 0, 0);
    }
    __syncthreads();

    int wc0 = w * 32;
    floatx4 acc1[4][2];
#pragma unroll
    for (int mt = 0; mt < 4; mt++)
#pragma unroll
        for (int nt = 0; nt < 2; nt++) acc1[mt][nt] = (floatx4){0.f, 0.f, 0.f, 0.f};
    float b1v[2];
#pragma unroll
    for (int nt = 0; nt < 2; nt++) b1v[nt] = b1[wc0 + nt * 16 + lrow];

#pragma unroll
    for (int ks = 0; ks < 8; ks++) {
        int koff = ks * 32 + lkb * 8;
        bhalf8 af[4], bf[2];
#pragma unroll
        for (int mt = 0; mt < 4; mt++) {
            int row = mt * 16 + lrow;
            int uidx = (row * 256 + koff) ^ ((row & 7) << 3);
            af[mt] = *reinterpret_cast<const bhalf8*>(&xs[uidx]);
        }
#pragma unroll
        for (int nt = 0; nt < 2; nt++) {
            int col = wc0 + nt * 16 + lrow;
            bf[nt] = *reinterpret_cast<const bhalf8*>(&W1T[(size_t)col * 256 + koff]);
        }
#pragma unroll
        for (int mt = 0; mt < 4; mt++)
#pragma unroll
            for (int nt = 0; nt < 2; nt++)
                acc1[mt][nt] = __builtin_amdgcn_mfma_f32_16x16x32_bf16(af[mt], bf[nt], acc1[mt][nt], 0, 0, 0);
    }
    __syncthreads();

#pragma unroll
    for (int mt = 0; mt < 4; mt++)
#pragma unroll
        for (int nt = 0; nt < 2; nt++) {
            int col = wc0 + nt * 16 + lrow;
#pragma unroll
            for (int r = 0; r < 4; r++) {
                int row = mt * 16 + lkb * 4 + r;
                float v = fmaxf(acc1[mt][nt][r] + b1v[nt], 0.f);
                int uidx = (row * 256 + col) ^ ((row & 7) << 3);
                xs[uidx] = f2bf(v);
            }
        }
    __syncthreads();

    int r0 = (w >> 1) * 16;
    int odd = w & 1;
    floatx4 acc2[2];
    acc2[0] = (floatx4){0.f, 0.f, 0.f, 0.f};
    acc2[1] = (floatx4){0.f, 0.f, 0.f, 0.f};
    int c0 = odd ? 32 : 0;
#pragma unroll
    for (int ks = 0; ks < 8; ks++) {
        int koff = ks * 32 + lkb * 8;
        int row = r0 + lrow;
        int uidx = (row * 256 + koff) ^ ((row & 7) << 3);
        bhalf8 a = *reinterpret_cast<const bhalf8*>(&xs[uidx]);
        bhalf8 b0 = *reinterpret_cast<const bhalf8*>(&W2T[(size_t)(c0 + lrow) * 320 + koff]);
        acc2[0] = __builtin_amdgcn_mfma_f32_16x16x32_bf16(a, b0, acc2[0], 0, 0, 0);
        if (!odd) {
            bhalf8 b1f = *reinterpret_cast<const bhalf8*>(&W2T[(size_t)(16 + lrow) * 320 + koff]);
            acc2[1] = __builtin_amdgcn_mfma_f32_16x16x32_bf16(a, b1f, acc2[1], 0, 0, 0);
        }
    }
#pragma unroll
    for (int ks = 0; ks < 2; ks++) {
        int koff = ks * 32 + lkb * 8;
        int row = r0 + lrow;
        int uidx = (row * 64 + koff) ^ ((row & 7) << 3);
        bhalf8 a = *reinterpret_cast<const bhalf8*>(&as[uidx]);
        bhalf8 b0 = *reinterpret_cast<const bhalf8*>(&W2T[(size_t)(c0 + lrow) * 320 + 256 + koff]);
        acc2[0] = __builtin_amdgcn_mfma_f32_16x16x32_bf16(a, b0, acc2[0], 0, 0, 0);
        if (!odd) {
            bhalf8 b1f = *reinterpret_cast<const bhalf8*>(&W2T[(size_t)(16 + lrow) * 320 + 256 + koff]);
            acc2[1] = __builtin_amdgcn_mfma_f32_16x16x32_bf16(a, b1f, acc2[1], 0, 0, 0);
        }
    }
    int ntend = odd ? 1 : 2;
#pragma unroll
    for (int nt = 0; nt < 2; nt++) {
        if (nt >= ntend) continue;
        int col = c0 + nt * 16 + lrow;
        if (col >= 40) continue;
        float bb = b2[col];
#pragma unroll
        for (int r = 0; r < 4; r++) {
            int row = n0 + r0 + lkb * 4 + r;
            if (row < N) out[(size_t)row * 40 + col] = acc2[nt][r] + bb;
        }
    }
}

extern "C" void kernel_launch(void* const* d_in, const int* in_sizes, int n_in,
                              void* d_out, int out_size, void* d_ws, size_t ws_size,
                              hipStream_t stream) {
    const float* x  = (const float*)d_in[0];
    const int*   ei = (const int*)d_in[1];
    const int*   ef = (const int*)d_in[2];
    const float* W1 = (const float*)d_in[3];
    const float* b1 = (const float*)d_in[4];
    const float* W2 = (const float*)d_in[5];
    const float* b2 = (const float*)d_in[6];
    float* out = (float*)d_out;

    const int HID = in_sizes[4];            // 256
    const int D   = in_sizes[3] / HID;      // 256
    const int N   = in_sizes[0] / D;        // 100000
    const int E   = in_sizes[1] / 2;        // 3200000
    (void)HID; (void)D;

    const int Escan  = min(N, E);                   // posmin truncation (r19 proof)
    const int nbuck  = (N + BROWS - 1) / BROWS;     // 782
    const int ntiles = (N + 63) / 64;               // 1563
    const int W      = (Escan + 63) / 64;           // 1563 bitmap words

    // workspace layout, 4-byte units (d_ws 16B-aligned); total ~118MB
    int* ws = (int*)d_ws;
    size_t o = 0;
    unsigned short* aggbf = (unsigned short*)(ws + o); o += (size_t)ntiles * 2048;
    int* pos = ws + o;                               o += N;
    int* rt = ws + o;                                o += N;
    int* cursorb = ws + o;                           o += nbuck;
    o = (o + 1) & ~(size_t)1;                        // 8B align for bitmap
    unsigned long long* bitmap = (unsigned long long*)(ws + o); o += 2 * (size_t)W;
    int* wordpfx = ws + o;                           o += W + 1;
    o = (o + 3) & ~(size_t)3;                        // 16B align
    unsigned* binned = (unsigned*)(ws + o);          o += (size_t)nbuck * BCAP;
    unsigned short* W1T = (unsigned short*)(ws + o); o += 32768;
    unsigned short* W2T = (unsigned short*)(ws + o); o += 7680;
    unsigned short* xbf = (unsigned short*)(ws + o); o += (size_t)ntiles * 8192;

    const int total4 = ntiles * 4096;
    const int nb_x = (total4 + 511) / 512;          // 12504 prep_x blocks (2 float4/thr)
    const int nb_i = (max(max(N, W), nbuck) + 255) / 256;  // 391 init blocks
    const int nb_w = 256;                           // weight-prep blocks (covers 65536 idx)

    hipLaunchKernelGGL(k_preps, dim3(nb_x + nb_i + nb_w), dim3(256), 0, stream,
                       x, xbf, W1, W2, W1T, W2T, pos, cursorb, bitmap,
                       N, total4, nbuck, W, E, nb_x, nb_i);
    hipLaunchKernelGGL(k_posmin, dim3((Escan + 255) / 256), dim3(256), 0, stream, ei, pos, Escan);
    hipLaunchKernelGGL(k_bitmap, dim3((N + 255) / 256), dim3(256), 0, stream, pos, bitmap, N, E);
    hipLaunchKernelGGL(k_scanw, dim3(1), dim3(1024), 0, stream, bitmap, wordpfx, W);
    hipLaunchKernelGGL(k_rt, dim3((N + 255) / 256), dim3(256), 0, stream, ei, pos, bitmap, wordpfx, rt, N);
    hipLaunchKernelGGL(k_mebin, dim3((E + EPB - 1) / EPB), dim3(TPB_MB), 0, stream,
                       ei, rt, ef, cursorb, binned, E, nbuck);
    hipLaunchKernelGGL(k_bgather, dim3(nbuck), dim3(256), 0, stream, cursorb, binned, aggbf, N);
    hipLaunchKernelGGL(k_fused, dim3(ntiles), dim3(512), 0, stream,
                       xbf, W1T, b1, W2T, b2, aggbf, out, N);
}

// Round 24
// 176.456 us; speedup vs baseline: 1.2104x; 1.0027x over previous
//
#include <hip/hip_runtime.h>
#include <hip/hip_bf16.h>

#define EPB  8192   // edges per k_mebin block
#define TPB_MB 1024 // 16 waves/block (r22)
#define BROWS 128   // rank-rows per bucket
#define BCAP 16384  // entry capacity per bucket (early buckets size-biased to ~8300
                    // mean; 8192 overflowed (r5/r6); 16384 ≈ 15σ)

typedef __attribute__((ext_vector_type(8))) short bhalf8;
typedef __attribute__((ext_vector_type(4))) float floatx4;

__device__ __forceinline__ unsigned short f2bf(float f) {
    __hip_bfloat16 h = __float2bfloat16(f);     // native RNE
    union { __hip_bfloat16 h; unsigned short u; } v;
    v.h = h;
    return v.u;
}

// ---------------- merged prep: xbf tiles | init | weights | ef->pv16 pack ----------------
// r24: 4th section packs ef's 4x int32 (16B/edge) into u16 pv (2B/edge) so the
// latency-bound mebin streams 2B/edge instead of 16B/edge.
__global__ void k_preps(const float* __restrict__ x, unsigned short* __restrict__ xbf,
                        const float* __restrict__ W1, const float* __restrict__ W2,
                        unsigned short* __restrict__ W1T, unsigned short* __restrict__ W2T,
                        int* __restrict__ pos, int* __restrict__ cursorb,
                        unsigned long long* __restrict__ bitmap,
                        const int* __restrict__ ef, unsigned short* __restrict__ pv16,
                        int N, int total4, int nbuck, int W, int E,
                        int nb_x, int nb_i, int nb_w) {
    int bid = blockIdx.x;
    int tid = threadIdx.x;
    if (bid < nb_x) {
        // ---- prep_x: f32 -> bf16, tile-major, XOR-pre-swizzled, zero-padded ----
#pragma unroll
        for (int j = 0; j < 2; j++) {
            int f = bid * 512 + j * 256 + tid;
            if (f >= total4) continue;
            int tile = f >> 12;
            int row = (f >> 6) & 63;
            int c4 = (f & 63) * 4;
            int grow = tile * 64 + row;
            float4 v = (grow < N) ? *reinterpret_cast<const float4*>(x + (size_t)grow * 256 + c4)
                                  : make_float4(0.f, 0.f, 0.f, 0.f);
            ushort4 bv;
            bv.x = f2bf(v.x); bv.y = f2bf(v.y); bv.z = f2bf(v.z); bv.w = f2bf(v.w);
            int uidx = (row * 256 + c4) ^ ((row & 7) << 3);
            *reinterpret_cast<ushort4*>(&xbf[(size_t)tile * 16384 + uidx]) = bv;
        }
    } else if (bid < nb_x + nb_i) {
        // ---- init: pos = E; cursorb[b] = b*BCAP; bitmap = 0 ----
        int i = (bid - nb_x) * 256 + tid;
        if (i < N) pos[i] = E;
        if (i < nbuck) cursorb[i] = i * BCAP;
        if (i < W) bitmap[i] = 0ull;
    } else if (bid < nb_x + nb_i + nb_w) {
        // ---- prep: W1T/W2T bf16 transposed weights ----
        int i = (bid - nb_x - nb_i) * 256 + tid;
        if (i < 256 * 256) {
            int c = i >> 8, k = i & 255;
            W1T[i] = f2bf(W1[k * 256 + c]);     // W1T[c][k] = W1[k][c]
        }
        if (i < 48 * 320) {
            int c = i / 320, k = i % 320;
            W2T[i] = (c < 40) ? f2bf(W2[k * 40 + c]) : (unsigned short)0;
        }
    } else {
        // ---- pack ef -> pv16 ----
        int e = (bid - nb_x - nb_i - nb_w) * 256 + tid;
        if (e < E) {
            int4 f = *reinterpret_cast<const int4*>(ef + 4 * (size_t)e);
            pv16[e] = (unsigned short)(f.x | (f.y << 4) | (f.z << 8) | (f.w << 12));
        }
    }
}

// ---------------- posmin over the FIRST Escan=min(N,E) edges only (proven r19) ----------------
__global__ void k_posmin(const int* __restrict__ ei, int* __restrict__ pos, int Escan) {
    int e = blockIdx.x * blockDim.x + threadIdx.x;
    if (e < Escan) {
        int s = ((const int2*)ei)[e].x;
        if (pos[s] > e) atomicMin(&pos[s], e);
    }
}

// ---------------- bitmap: set bit pos[n] for found nodes (proven) ----------------
__global__ void k_bitmap(const int* __restrict__ pos, unsigned long long* __restrict__ bitmap,
                         int N, int E) {
    int n = blockIdx.x * blockDim.x + threadIdx.x;
    if (n < N) {
        int p = pos[n];
        if (p < E) atomicOr(&bitmap[p >> 6], 1ull << (p & 63));
    }
}

// ---------------- single-block popcount-prefix over W<=~4K words (proven r23) ----------------
__global__ void k_scanw(const unsigned long long* __restrict__ bitmap,
                        int* __restrict__ wordpfx, int W) {
    __shared__ int part[1024];
    const int T = 1024;
    int t = threadIdx.x;
    int per = (W + T - 1) / T;
    int s0 = t * per, s1 = min(s0 + per, W);
    int sum = 0;
    for (int i = s0; i < s1; i++) sum += __popcll(bitmap[i]);
    part[t] = sum;
    __syncthreads();
    for (int off = 1; off < T; off <<= 1) {
        int v = 0;
        if (t >= off) v = part[t - off];
        __syncthreads();
        part[t] += v;
        __syncthreads();
    }
    int run = part[t] - sum;       // exclusive prefix for this thread's chunk
    for (int i = s0; i < s1; i++) {
        wordpfx[i] = run;
        run += __popcll(bitmap[i]);
    }
    if (t == T - 1) wordpfx[W] = part[T - 1];
}

// ---------------- rt[n] = bitmapRank(pos[seg[n]]) (proven r22) ----------------
__global__ void k_rt(const int* __restrict__ ei, const int* __restrict__ pos,
                     const unsigned long long* __restrict__ bitmap,
                     const int* __restrict__ wordpfx, int* __restrict__ rt, int N) {
    int n = blockIdx.x * blockDim.x + threadIdx.x;
    if (n >= N) return;
    int sn = ((const int2*)ei)[n].x;
    int p = pos[sn];
    int w = p >> 6, off = p & 63;
    unsigned long long mask = (1ull << off) - 1ull;
    rt[n] = wordpfx[w] + __popcll(bitmap[w] & mask);
}

// ---------------- mebin: gather + bucket binning, LDS-staged ----------------
// r24: consumes pre-packed pv16 (2B/edge) instead of int4 ef (16B/edge).
__global__ __launch_bounds__(TPB_MB, 4) void k_mebin(const int* __restrict__ ei,
                                                     const int* __restrict__ rt,
                                                     const unsigned short* __restrict__ pv16,
                                                     int* __restrict__ cursorb,
                                                     unsigned* __restrict__ binned,
                                                     int E, int nbuck) {
    __shared__ unsigned lmp[EPB];          // 32KB: (m<<16)|pv per staged edge
    __shared__ int lcnt[800];
    __shared__ int lbase[800];
    __shared__ int lfill[800];
    int tid = threadIdx.x;
    int base = blockIdx.x * EPB;
    for (int b = tid; b < nbuck; b += TPB_MB) { lcnt[b] = 0; lfill[b] = 0; }
    __syncthreads();
    // gather + stage + count: 8 edges/thread in 2 batches of 4 independent chains
#pragma unroll
    for (int jj = 0; jj < 2; jj++) {
        int l0 = (jj * 4 + 0) * TPB_MB + tid;
        int l1 = (jj * 4 + 1) * TPB_MB + tid;
        int l2 = (jj * 4 + 2) * TPB_MB + tid;
        int l3 = (jj * 4 + 3) * TPB_MB + tid;
        int e0 = base + l0, e1 = base + l1, e2 = base + l2, e3 = base + l3;
        int s0 = 0, s1 = 0, s2 = 0, s3 = 0;
        if (e0 < E) s0 = ((const int2*)ei)[e0].x;
        if (e1 < E) s1 = ((const int2*)ei)[e1].x;
        if (e2 < E) s2 = ((const int2*)ei)[e2].x;
        if (e3 < E) s3 = ((const int2*)ei)[e3].x;
        int m0 = 0, m1 = 0, m2 = 0, m3 = 0;
        if (e0 < E) m0 = rt[s0];
        if (e1 < E) m1 = rt[s1];
        if (e2 < E) m2 = rt[s2];
        if (e3 < E) m3 = rt[s3];
        unsigned p0 = 0, p1 = 0, p2 = 0, p3 = 0;
        if (e0 < E) p0 = pv16[e0];
        if (e1 < E) p1 = pv16[e1];
        if (e2 < E) p2 = pv16[e2];
        if (e3 < E) p3 = pv16[e3];
        if (e0 < E) { lmp[l0] = ((unsigned)m0 << 16) | p0; atomicAdd(&lcnt[m0 >> 7], 1); }
        if (e1 < E) { lmp[l1] = ((unsigned)m1 << 16) | p1; atomicAdd(&lcnt[m1 >> 7], 1); }
        if (e2 < E) { lmp[l2] = ((unsigned)m2 << 16) | p2; atomicAdd(&lcnt[m2 >> 7], 1); }
        if (e3 < E) { lmp[l3] = ((unsigned)m3 << 16) | p3; atomicAdd(&lcnt[m3 >> 7], 1); }
    }
    __syncthreads();
    // claim contiguous global runs per bucket
    for (int b = tid; b < nbuck; b += TPB_MB) {
        int c = lcnt[b];
        lbase[b] = (c > 0) ? atomicAdd(&cursorb[b], c) : 0;
    }
    __syncthreads();
    // write from LDS only
#pragma unroll
    for (int j = 0; j < EPB / TPB_MB; j++) {
        int li = j * TPB_MB + tid;
        if (base + li < E) {
            unsigned v = lmp[li];
            int b = v >> 23;
            int off = atomicAdd(&lfill[b], 1);
            long long slot = (long long)lbase[b] + off;
            if (slot < (long long)(b + 1) * BCAP)   // overflow guard
                binned[slot] = v & 0x7FFFFFu;       // (m&127)<<16 | pv
        }
    }
}

// ---------------- bucket gather: LDS histogram -> bf16 pre-swizzled agg tiles (proven) ----------------
__global__ __launch_bounds__(256) void k_bgather(const int* __restrict__ cursorb,
                                                 const unsigned* __restrict__ binned,
                                                 unsigned short* __restrict__ aggbf, int N) {
    __shared__ int hist[BROWS * 64];   // 32KB
    int tid = threadIdx.x;
    int b = blockIdx.x;
    int m0 = b * BROWS;
    for (int i = tid; i < BROWS * 64; i += 256) hist[i] = 0;
    __syncthreads();
    int r0 = b * BCAP;
    int r1 = min(cursorb[b], (b + 1) * BCAP);
    for (int i = r0 + tid; i < r1; i += 256) {
        unsigned v = binned[i];
        int lr = (int)(v >> 16) << 6;           // local row (m&127) * 64
        atomicAdd(&hist[lr + (v & 15u)], 1);
        atomicAdd(&hist[lr + 16 + ((v >> 4) & 15u)], 1);
        atomicAdd(&hist[lr + 32 + ((v >> 8) & 15u)], 1);
        atomicAdd(&hist[lr + 48 + ((v >> 12) & 15u)], 1);
    }
    __syncthreads();
    int rows = min(BROWS, N - m0);
    for (int i = tid; i < rows * 64; i += 256) {
        int lr = i >> 6, col = i & 63;
        int tile = (m0 + lr) >> 6;
        int row = (m0 + lr) & 63;
        int uidx = (row * 64 + col) ^ ((row & 7) << 3);
        aggbf[(size_t)tile * 4096 + uidx] = f2bf((float)hist[i]);
    }
}

// ---------------- fused MFMA (r13/r14/r16 proven: async global_load_lds staging) ----------------
__global__ __launch_bounds__(512) void k_fused(const unsigned short* __restrict__ xbf,
                                               const unsigned short* __restrict__ W1T,
                                               const float* __restrict__ b1,
                                               const unsigned short* __restrict__ W2T,
                                               const float* __restrict__ b2,
                                               const unsigned short* __restrict__ aggbf,
                                               float* __restrict__ out, int N) {
    __shared__ __align__(16) unsigned short xs[64 * 256];
    __shared__ __align__(16) unsigned short as[64 * 64];
    int tid = threadIdx.x;
    int lane = tid & 63;
    int w = tid >> 6;
    int lrow = lane & 15, lkb = lane >> 4;
    int n0 = blockIdx.x * 64;

    {
        const char* xg = (const char*)(xbf + (size_t)blockIdx.x * 16384);
#pragma unroll
        for (int j = 0; j < 4; j++) {
            int ch = w * 4 + j;
            __builtin_amdgcn_global_load_lds(
                (const __attribute__((address_space(1))) unsigned*)(xg + ch * 1024 + lane * 16),
                (__attribute__((address_space(3))) unsigned*)((char*)xs + ch * 1024),
                16, 0, 0);
        }
        const char* ag = (const char*)(aggbf + (size_t)blockIdx.x * 4096);
        __builtin_amdgcn_global_load_lds(
            (const __attribute__((address_space(1))) unsigned*)(ag + w * 1024 + lane * 16),
            (__attribute__((address_space(3))) unsigned*)((char*)as + w * 1024),
            16, 0, 0);
    }
    __syncthreads();

    int wc0 = w * 32;
    floatx4 acc1[4][2];
#pragma unroll
    for (int mt = 0; mt < 4; mt++)
#pragma unroll
        for (int nt = 0; nt < 2; nt++) acc1[mt][nt] = (floatx4){0.f, 0.f, 0.f, 0.f};
    float b1v[2];
#pragma unroll
    for (int nt = 0; nt < 2; nt++) b1v[nt] = b1[wc0 + nt * 16 + lrow];

#pragma unroll
    for (int ks = 0; ks < 8; ks++) {
        int koff = ks * 32 + lkb * 8;
        bhalf8 af[4], bf[2];
#pragma unroll
        for (int mt = 0; mt < 4; mt++) {
            int row = mt * 16 + lrow;
            int uidx = (row * 256 + koff) ^ ((row & 7) << 3);
            af[mt] = *reinterpret_cast<const bhalf8*>(&xs[uidx]);
        }
#pragma unroll
        for (int nt = 0; nt < 2; nt++) {
            int col = wc0 + nt * 16 + lrow;
            bf[nt] = *reinterpret_cast<const bhalf8*>(&W1T[(size_t)col * 256 + koff]);
        }
#pragma unroll
        for (int mt = 0; mt < 4; mt++)
#pragma unroll
            for (int nt = 0; nt < 2; nt++)
                acc1[mt][nt] = __builtin_amdgcn_mfma_f32_16x16x32_bf16(af[mt], bf[nt], acc1[mt][nt], 0, 0, 0);
    }
    __syncthreads();

#pragma unroll
    for (int mt = 0; mt < 4; mt++)
#pragma unroll
        for (int nt = 0; nt < 2; nt++) {
            int col = wc0 + nt * 16 + lrow;
#pragma unroll
            for (int r = 0; r < 4; r++) {
                int row = mt * 16 + lkb * 4 + r;
                float v = fmaxf(acc1[mt][nt][r] + b1v[nt], 0.f);
                int uidx = (row * 256 + col) ^ ((row & 7) << 3);
                xs[uidx] = f2bf(v);
            }
        }
    __syncthreads();

    int r0 = (w >> 1) * 16;
    int odd = w & 1;
    floatx4 acc2[2];
    acc2[0] = (floatx4){0.f, 0.f, 0.f, 0.f};
    acc2[1] = (floatx4){0.f, 0.f, 0.f, 0.f};
    int c0 = odd ? 32 : 0;
#pragma unroll
    for (int ks = 0; ks < 8; ks++) {
        int koff = ks * 32 + lkb * 8;
        int row = r0 + lrow;
        int uidx = (row * 256 + koff) ^ ((row & 7) << 3);
        bhalf8 a = *reinterpret_cast<const bhalf8*>(&xs[uidx]);
        bhalf8 b0 = *reinterpret_cast<const bhalf8*>(&W2T[(size_t)(c0 + lrow) * 320 + koff]);
        acc2[0] = __builtin_amdgcn_mfma_f32_16x16x32_bf16(a, b0, acc2[0], 0, 0, 0);
        if (!odd) {
            bhalf8 b1f = *reinterpret_cast<const bhalf8*>(&W2T[(size_t)(16 + lrow) * 320 + koff]);
            acc2[1] = __builtin_amdgcn_mfma_f32_16x16x32_bf16(a, b1f, acc2[1], 0, 0, 0);
        }
    }
#pragma unroll
    for (int ks = 0; ks < 2; ks++) {
        int koff = ks * 32 + lkb * 8;
        int row = r0 + lrow;
        int uidx = (row * 64 + koff) ^ ((row & 7) << 3);
        bhalf8 a = *reinterpret_cast<const bhalf8*>(&as[uidx]);
        bhalf8 b0 = *reinterpret_cast<const bhalf8*>(&W2T[(size_t)(c0 + lrow) * 320 + 256 + koff]);
        acc2[0] = __builtin_amdgcn_mfma_f32_16x16x32_bf16(a, b0, acc2[0], 0, 0, 0);
        if (!odd) {
            bhalf8 b1f = *reinterpret_cast<const bhalf8*>(&W2T[(size_t)(16 + lrow) * 320 + 256 + koff]);
            acc2[1] = __builtin_amdgcn_mfma_f32_16x16x32_bf16(a, b1f, acc2[1], 0, 0, 0);
        }
    }
    int ntend = odd ? 1 : 2;
#pragma unroll
    for (int nt = 0; nt < 2; nt++) {
        if (nt >= ntend) continue;
        int col = c0 + nt * 16 + lrow;
        if (col >= 40) continue;
        float bb = b2[col];
#pragma unroll
        for (int r = 0; r < 4; r++) {
            int row = n0 + r0 + lkb * 4 + r;
            if (row < N) out[(size_t)row * 40 + col] = acc2[nt][r] + bb;
        }
    }
}

extern "C" void kernel_launch(void* const* d_in, const int* in_sizes, int n_in,
                              void* d_out, int out_size, void* d_ws, size_t ws_size,
                              hipStream_t stream) {
    const float* x  = (const float*)d_in[0];
    const int*   ei = (const int*)d_in[1];
    const int*   ef = (const int*)d_in[2];
    const float* W1 = (const float*)d_in[3];
    const float* b1 = (const float*)d_in[4];
    const float* W2 = (const float*)d_in[5];
    const float* b2 = (const float*)d_in[6];
    float* out = (float*)d_out;

    const int HID = in_sizes[4];            // 256
    const int D   = in_sizes[3] / HID;      // 256
    const int N   = in_sizes[0] / D;        // 100000
    const int E   = in_sizes[1] / 2;        // 3200000
    (void)HID; (void)D;

    const int Escan  = min(N, E);                   // posmin truncation (r19 proof)
    const int nbuck  = (N + BROWS - 1) / BROWS;     // 782
    const int ntiles = (N + 63) / 64;               // 1563
    const int W      = (Escan + 63) / 64;           // 1563 bitmap words

    // workspace layout, 4-byte units (d_ws 16B-aligned); total ~125MB
    int* ws = (int*)d_ws;
    size_t o = 0;
    unsigned short* aggbf = (unsigned short*)(ws + o); o += (size_t)ntiles * 2048;
    int* pos = ws + o;                               o += N;
    int* rt = ws + o;                                o += N;
    int* cursorb = ws + o;                           o += nbuck;
    o = (o + 1) & ~(size_t)1;                        // 8B align for bitmap
    unsigned long long* bitmap = (unsigned long long*)(ws + o); o += 2 * (size_t)W;
    int* wordpfx = ws + o;                           o += W + 1;
    o = (o + 3) & ~(size_t)3;                        // 16B align
    unsigned* binned = (unsigned*)(ws + o);          o += (size_t)nbuck * BCAP;
    unsigned short* pv16 = (unsigned short*)(ws + o); o += ((size_t)E + 1) / 2;
    o = (o + 3) & ~(size_t)3;                        // 16B align
    unsigned short* W1T = (unsigned short*)(ws + o); o += 32768;
    unsigned short* W2T = (unsigned short*)(ws + o); o += 7680;
    unsigned short* xbf = (unsigned short*)(ws + o); o += (size_t)ntiles * 8192;

    const int total4 = ntiles * 4096;
    const int nb_x = (total4 + 511) / 512;          // 12504 prep_x blocks (2 float4/thr)
    const int nb_i = (max(max(N, W), nbuck) + 255) / 256;  // 391 init blocks
    const int nb_w = 256;                           // weight-prep blocks (covers 65536 idx)
    const int nb_f = (E + 255) / 256;               // 12500 ef-pack blocks

    hipLaunchKernelGGL(k_preps, dim3(nb_x + nb_i + nb_w + nb_f), dim3(256), 0, stream,
                       x, xbf, W1, W2, W1T, W2T, pos, cursorb, bitmap, ef, pv16,
                       N, total4, nbuck, W, E, nb_x, nb_i, nb_w);
    hipLaunchKernelGGL(k_posmin, dim3((Escan + 255) / 256), dim3(256), 0, stream, ei, pos, Escan);
    hipLaunchKernelGGL(k_bitmap, dim3((N + 255) / 256), dim3(256), 0, stream, pos, bitmap, N, E);
    hipLaunchKernelGGL(k_scanw, dim3(1), dim3(1024), 0, stream, bitmap, wordpfx, W);
    hipLaunchKernelGGL(k_rt, dim3((N + 255) / 256), dim3(256), 0, stream, ei, pos, bitmap, wordpfx, rt, N);
    hipLaunchKernelGGL(k_mebin, dim3((E + EPB - 1) / EPB), dim3(TPB_MB), 0, stream,
                       ei, rt, pv16, cursorb, binned, E, nbuck);
    hipLaunchKernelGGL(k_bgather, dim3(nbuck), dim3(256), 0, stream, cursorb, binned, aggbf, N);
    hipLaunchKernelGGL(k_fused, dim3(ntiles), dim3(512), 0, stream,
                       xbf, W1T, b1, W2T, b2, aggbf, out, N);
}